// Round 6
// baseline (171.087 us; speedup 1.0000x reference)
//
#include <hip/hip_runtime.h>
#include <cstdint>
#include <cstddef>

#define BATCH 2048
#define NZ 128
#define NGEN 8
#define GRPS 32                 // samples per group (same generator)
#define MAXG 72                 // max padded groups
#define NCT 13                  // fc2 col tiles of 128 (12 full + tail 32)
#define H2_ELEMS 1792           // 32*7*8 (x padded 7->8) per sample, f16
#define WS_H1_OFF 16384                                  // h1: 72*8192 fp32
#define WS_H2_OFF (16384 + MAXG * 8192 * 4)              // 2375680
#define WS_W2T_OFF (WS_H2_OFF + BATCH * H2_ELEMS * 2)    // 9715712
#define W2T_GSTRIDE (1568 * 256)                         // fp16 elems per gen
#define NB_W2T (NGEN * 49)                               // 392
#define NB_PREP (NB_W2T + MAXG * 4)                      // 680
// packed f16x2 conv weights (pairs over input channel), per generator:
//   wpk1[g][cip16][a4][co16][c4], wpk2[g][cip8][a4][co8][c4], wpk3[g][cip4][9]
#define WS_WPK1_OFF (WS_W2T_OFF + NGEN * W2T_GSTRIDE * 2)  // 16138240 (16B aligned)
#define WS_WPK2_OFF (WS_WPK1_OFF + NGEN * 4096 * 4)
#define WS_WPK3_OFF (WS_WPK2_OFF + NGEN * 1024 * 4)
#define PS 168                  // fc2 epilogue LDS row stride (u16), 336B = 16B-mult

typedef unsigned int u32;
typedef unsigned short u16;
typedef unsigned long long u64;
typedef _Float16 f16x8 __attribute__((ext_vector_type(8)));
typedef _Float16 f16x4 __attribute__((ext_vector_type(4)));
typedef _Float16 f16x2 __attribute__((ext_vector_type(2)));
typedef float f32x4 __attribute__((ext_vector_type(4)));

__device__ __forceinline__ float lrelu(float x) { return fmaxf(x, 0.2f * x); }
__device__ __forceinline__ u16 f16b(float f) {
    _Float16 h = (_Float16)f;
    return __builtin_bit_cast(u16, h);
}
__device__ __forceinline__ u32 pk2(float a, float b) {
    f16x2 v; v[0] = (_Float16)a; v[1] = (_Float16)b;
    return __builtin_bit_cast(u32, v);
}
// 2-wide f16 dot with f32 accumulate: v_dot2_f32_f16 (2 MACs/instr, full rate)
__device__ __forceinline__ float dot2(u32 a, u32 b, float c) {
#if __has_builtin(__builtin_amdgcn_fdot2)
    return __builtin_amdgcn_fdot2(__builtin_bit_cast(f16x2, a),
                                  __builtin_bit_cast(f16x2, b), c, false);
#else
    float d;
    asm("v_dot2_f32_f16 %0, %1, %2, %3" : "=v"(d) : "v"(a), "v"(b), "v"(c));
    return d;
#endif
}
__device__ __forceinline__ float fast_tanh(float x) {
    x = fminf(fmaxf(x, -9.f), 9.f);
    const float e = __expf(2.f * x);
    return (e - 1.f) / (e + 1.f);
}
// h2 storage offset for fc2 column n (strictly monotone in n)
__device__ __forceinline__ int h2off(int n) {
    const int ci = n / 49, rm = n % 49;
    return ci * 56 + (rm / 7) * 8 + (rm % 7);
}

// ---------------------------------------------------------------------------
// Kernel 1: prep. Roles by blockIdx:
//   [0, NB_W2T)            : W2 transpose -> W2T f16
//   [NB_W2T, NB_PREP)      : grouped FC1 (locally recomputes binning)
//   [NB_PREP, NB_PREP+NGEN): conv-weight f16x2 packing
//   NB_PREP+NGEN           : bin publisher (writes wsi for fc2/conv)
// ---------------------------------------------------------------------------
__global__ __launch_bounds__(256) void prep_kernel(
    const float* __restrict__ z, const int* __restrict__ g_idx,
    const float* __restrict__ W1, const float* __restrict__ b1,
    const float* __restrict__ W2, int* __restrict__ wsi,
    float* __restrict__ h1g, _Float16* __restrict__ W2T,
    const float* __restrict__ cw1, const float* __restrict__ cw2,
    const float* __restrict__ cw3,
    u32* __restrict__ wpk1, u32* __restrict__ wpk2, u32* __restrict__ wpk3)
{
    __shared__ __align__(16) char pmem[16896];   // roles alias this region

    const int tid = threadIdx.x;
    const int bx = blockIdx.x;

    if (bx < NB_W2T) {
        // ---- W2 transpose role: W2[g][k256][n1568] fp32 -> W2T[g][n][k] fp16
        _Float16 (*t)[264] = (_Float16 (*)[264])pmem;   // 16.5 KB
        const int g = bx / 49;
        const int n0 = (bx % 49) * 32;
        const float* src = W2 + (size_t)g * 256 * 1568;
        const int nl = tid & 31, kh = tid >> 5;
        #pragma unroll 8
        for (int p = 0; p < 32; ++p) {
            const int k = p * 8 + kh;
            t[nl][k] = (_Float16)src[(size_t)k * 1568 + n0 + nl];
        }
        __syncthreads();
        _Float16* dst = W2T + (size_t)g * W2T_GSTRIDE + (size_t)n0 * 256;
        #pragma unroll
        for (int ii = 0; ii < 4; ++ii) {
            const int i = tid + 256 * ii;           // 1024 chunks of 16B
            const int n = i >> 5, kc = i & 31;
            *(uint4*)(dst + (size_t)n * 256 + kc * 8) = *(const uint4*)&t[n][kc * 8];
        }
        return;
    }

    if (bx >= NB_PREP && bx < NB_PREP + NGEN) {
        // ---- conv-weight packing role: pair input channels into f16x2 ----
        const int g = bx - NB_PREP;
        const float* c1p = cw1 + g * 8192;             // [32ci][16co][4][4]
        u32* o1 = wpk1 + g * 4096;
        for (int i = tid; i < 4096; i += 256) {
            const int cip = i >> 8, a = (i >> 6) & 3, co = (i >> 2) & 15, c = i & 3;
            const float* s = c1p + cip * 512 + co * 16 + a * 4 + c;
            o1[i] = pk2(s[0], s[256]);
        }
        const float* c2p = cw2 + g * 2048;             // [16ci][8co][4][4]
        u32* o2 = wpk2 + g * 1024;
        for (int i = tid; i < 1024; i += 256) {
            const int cip = i >> 7, a = (i >> 5) & 3, co = (i >> 2) & 7, c = i & 3;
            const float* s = c2p + cip * 256 + co * 16 + a * 4 + c;
            o2[i] = pk2(s[0], s[128]);
        }
        if (tid < 36) {                                // [8ci][1co][3][3]
            const int cip = tid / 9, r = tid % 9;
            const float* s = cw3 + g * 72 + cip * 18 + r;
            wpk3[g * 36 + tid] = pk2(s[0], s[9]);
        }
        return;
    }

    // ---- local binning (shared by fc1 role and bin-publisher role) ----
    u16* rank       = (u16*)pmem;                       // [2048] 4096 B
    int (*wcnt)[NGEN]  = (int (*)[NGEN])(pmem + 4096);  // [4][8]
    int (*wboff)[NGEN] = (int (*)[NGEN])(pmem + 4224);  // [4][8]
    int* pbase      = (int*)(pmem + 4352);              // [9]
    const int w = tid >> 6, lane = tid & 63;
    if (tid < 4 * NGEN) wcnt[tid >> 3][tid & 7] = 0;
    __syncthreads();
    const u64 lt = ((u64)1 << lane) - 1;
    #pragma unroll
    for (int r = 0; r < 8; ++r) {
        const int b = r * 256 + tid;
        const int gg = g_idx[b];
        u64 m[NGEN];
        #pragma unroll
        for (int k = 0; k < NGEN; ++k) m[k] = __ballot(gg == k);
        rank[b] = (u16)((int)__popcll(m[gg] & lt) + wcnt[w][gg]);
        if (lane < NGEN) wcnt[w][lane] += (int)__popcll(m[lane]);
    }
    __syncthreads();
    if (tid == 0) {
        int acc = 0;
        for (int g = 0; g < NGEN; ++g) {
            pbase[g] = acc;
            const int tot = wcnt[0][g] + wcnt[1][g] + wcnt[2][g] + wcnt[3][g];
            acc += ((tot + GRPS - 1) / GRPS) * GRPS;
        }
        pbase[NGEN] = acc;
    }
    __syncthreads();
    if (tid < 32) {
        const int ww = tid >> 3, g = tid & 7;
        int off = pbase[g];
        for (int w2 = 0; w2 < ww; ++w2) off += wcnt[w2][g];
        wboff[ww][g] = off;
    }
    __syncthreads();

    if (bx >= NB_PREP + NGEN) {
        // ---- bin-publisher role: write wsi for fc2/conv ----
        if (tid == 0) wsi[0] = pbase[NGEN];
        for (int i = tid; i < MAXG * GRPS; i += 256) wsi[16 + i] = -1;
        __syncthreads();
        #pragma unroll
        for (int r = 0; r < 8; ++r) {
            const int b = r * 256 + tid;
            const int gg = g_idx[b];
            wsi[16 + wboff[w][gg] + (int)rank[b]] = b;
        }
        return;
    }

    // ---- FC1 role (grouped): (group, 8-sample slice) ----
    const int bx2 = bx - NB_W2T;
    const int grp = bx2 >> 2;
    const int s0 = (bx2 & 3) * 8;
    if (grp * GRPS >= pbase[NGEN]) return;

    int gsel = 0;
    #pragma unroll
    for (int g = 1; g < NGEN; ++g) if (grp * GRPS >= pbase[g]) gsel = g;

    int* sb = (int*)(pmem + 4400);                     // [8]
    float (*zst)[12] = (float (*)[12])(pmem + 4608);   // [128][12] 6144 B
    if (tid < 8) sb[tid] = -1;
    __syncthreads();
    const int base = grp * GRPS + s0;
    #pragma unroll
    for (int r = 0; r < 8; ++r) {
        const int b = r * 256 + tid;
        const int gg = g_idx[b];
        const int rel = wboff[w][gg] + (int)rank[b] - base;
        if ((unsigned)rel < 8u) sb[rel] = b;
    }
    __syncthreads();

    const float* W1g = W1 + gsel * (NZ * 256);
    const float* b1g = b1 + gsel * 256;

    {   // stage z: 8 samples x 128 = 256 float4, one per thread
        const int s = tid >> 5, f = tid & 31;
        float4 v = make_float4(0.f, 0.f, 0.f, 0.f);
        if (sb[s] >= 0) v = *(const float4*)(z + (size_t)sb[s] * NZ + 4 * f);
        zst[4 * f + 0][s] = v.x; zst[4 * f + 1][s] = v.y;
        zst[4 * f + 2][s] = v.z; zst[4 * f + 3][s] = v.w;
    }
    __syncthreads();

    const int c = tid;
    float acc[8];
    #pragma unroll
    for (int s = 0; s < 8; ++s) acc[s] = 0.f;
    const float* wp = W1g + c;
    #pragma unroll 4
    for (int k = 0; k < NZ; ++k) {
        const float wv = wp[k * 256];
        float av[8];
        *(float4*)&av[0] = *(const float4*)&zst[k][0];
        *(float4*)&av[4] = *(const float4*)&zst[k][4];
        #pragma unroll
        for (int s = 0; s < 8; ++s) acc[s] += av[s] * wv;
    }
    const float bv = b1g[c];
    float* hp = h1g + (size_t)grp * 8192 + (size_t)s0 * 256 + c;
    #pragma unroll
    for (int s = 0; s < 8; ++s) hp[s * 256] = lrelu(acc[s] + bv);
}

// ---------------------------------------------------------------------------
// Kernel 2: FC2 via fp16 MFMA 16x16x32 — DIRECT-A form (no LDS staging).
// A-fragment layout for mfma_f32_16x16x32_f16 is 8 consecutive k per lane
// (m=lane&15, k=kq*32+(lane>>4)*8+j), which in h1g row-major is exactly two
// adjacent float4 loads -> load A straight from L2-hot h1g, convert in-reg.
// Deletes the stage barrier + 16KB afrag LDS; only the epilogue pst remains.
// Numerics bit-identical to the staged form (same RTE f32->f16 cast).
// ---------------------------------------------------------------------------
__global__ __launch_bounds__(256) void fc2_kernel(
    const int* __restrict__ g_idx,
    const _Float16* __restrict__ W2T, const float* __restrict__ b2,
    const int* __restrict__ wsi, const float* __restrict__ h1g,
    u16* __restrict__ h2g)
{
    __shared__ __align__(16) u16 pst[GRPS][PS];   // 10.75 KB
    __shared__ int sb[GRPS];
    __shared__ int sG;

    const int tid = threadIdx.x;
    const int grp = blockIdx.x / NCT;
    const int tile = blockIdx.x % NCT;
    if (grp * GRPS >= wsi[0]) return;   // whole block uniform: before barriers

    if (tid == 0) sG = g_idx[wsi[16 + grp * GRPS]];
    if (tid < GRPS) sb[tid] = wsi[16 + grp * GRPS + tid];
    __syncthreads();
    const _Float16* W2Tg = W2T + (size_t)sG * W2T_GSTRIDE;
    const float* b2g = b2 + sG * 1568;

    const int wave = tid >> 6;
    const int lane = tid & 63;
    const int q = lane >> 4;
    const int nl = lane & 15;
    const int nb0 = tile * 128 + 2 * wave * 16;
    const int nb1 = nb0 + 16;
    const bool act0 = nb0 < 1568, act1 = nb1 < 1568;

    // per-lane A row pointers: m = nl (rows 0-15) and nl+16 (rows 16-31)
    const float* ar0 = h1g + (size_t)grp * 8192 + (size_t)nl * 256 + q * 8;
    const float* ar1 = ar0 + 16 * 256;
    const _Float16* bp0 = W2Tg + (size_t)(nb0 + nl) * 256 + q * 8;
    const _Float16* bp1 = W2Tg + (size_t)(nb1 + nl) * 256 + q * 8;

    f32x4 accA0 = {0.f, 0.f, 0.f, 0.f}, accB0 = accA0;
    f32x4 accA1 = accA0, accB1 = accA0;
    #pragma unroll
    for (int kq = 0; kq < 8; ++kq) {
        const float4 a0lo = *(const float4*)(ar0 + kq * 32);
        const float4 a0hi = *(const float4*)(ar0 + kq * 32 + 4);
        const float4 a1lo = *(const float4*)(ar1 + kq * 32);
        const float4 a1hi = *(const float4*)(ar1 + kq * 32 + 4);
        f16x8 a0, a1;
        a0[0] = (_Float16)a0lo.x; a0[1] = (_Float16)a0lo.y;
        a0[2] = (_Float16)a0lo.z; a0[3] = (_Float16)a0lo.w;
        a0[4] = (_Float16)a0hi.x; a0[5] = (_Float16)a0hi.y;
        a0[6] = (_Float16)a0hi.z; a0[7] = (_Float16)a0hi.w;
        a1[0] = (_Float16)a1lo.x; a1[1] = (_Float16)a1lo.y;
        a1[2] = (_Float16)a1lo.z; a1[3] = (_Float16)a1lo.w;
        a1[4] = (_Float16)a1hi.x; a1[5] = (_Float16)a1hi.y;
        a1[6] = (_Float16)a1hi.z; a1[7] = (_Float16)a1hi.w;
        if (act0) {
            const f16x8 b = *(const f16x8*)(bp0 + kq * 32);
            accA0 = __builtin_amdgcn_mfma_f32_16x16x32_f16(a0, b, accA0, 0, 0, 0);
            accB0 = __builtin_amdgcn_mfma_f32_16x16x32_f16(a1, b, accB0, 0, 0, 0);
        }
        if (act1) {
            const f16x8 b = *(const f16x8*)(bp1 + kq * 32);
            accA1 = __builtin_amdgcn_mfma_f32_16x16x32_f16(a0, b, accA1, 0, 0, 0);
            accB1 = __builtin_amdgcn_mfma_f32_16x16x32_f16(a1, b, accB1, 0, 0, 0);
        }
    }

    const int nstart = tile * 128;
    const int nend = (nstart + 128 < 1568) ? nstart + 128 : 1568;
    const int offLo = h2off(nstart), offHi = h2off(nend - 1);
    const int lo8 = offLo & ~7;

    if (act0) {
        const int n = nb0 + nl;
        const float bias = b2g[n];
        u16* pp = &pst[0][0] + (h2off(n) - lo8);
        #pragma unroll
        for (int reg = 0; reg < 4; ++reg) {
            pp[(q * 4 + reg) * PS]        = f16b(lrelu(accA0[reg] + bias));
            pp[(16 + q * 4 + reg) * PS]   = f16b(lrelu(accB0[reg] + bias));
        }
    }
    if (act1) {
        const int n = nb1 + nl;
        const float bias = b2g[n];
        u16* pp = &pst[0][0] + (h2off(n) - lo8);
        #pragma unroll
        for (int reg = 0; reg < 4; ++reg) {
            pp[(q * 4 + reg) * PS]        = f16b(lrelu(accA1[reg] + bias));
            pp[(16 + q * 4 + reg) * PS]   = f16b(lrelu(accB1[reg] + bias));
        }
    }
    __syncthreads();

    // ---- coalesced copy-out: 8 threads per sample ----
    {
        const int s = tid >> 3, p = tid & 7;
        const int bb = sb[s];
        if (bb >= 0) {
            u16* row = h2g + (size_t)bb * H2_ELEMS;
            const u16* ps = &pst[s][0] - lo8;          // index by off directly
            const int c0 = (offLo + 7) & ~7;           // first aligned chunk
            const int c1 = (offHi + 1) & ~7;           // end of aligned chunks
            for (int o = offLo + p; o < c0 && o <= offHi; o += 8) row[o] = ps[o];
            const int t0 = (c1 > offLo) ? c1 : offLo;
            for (int o = t0 + p; o <= offHi; o += 8) row[o] = ps[o];
            for (int c = c0 + p * 8; c + 8 <= c1; c += 64)
                *(uint4*)(row + c) = *(const uint4*)(ps + c);
        }
    }
}

// ---------------------------------------------------------------------------
// conv2 merged full-width pass: rr loaded ONCE per (cip,a), acc[28].
// Output written into zero-padded c2s at column 1+x (stride 30).
// ---------------------------------------------------------------------------
__device__ __forceinline__ void conv2p_full(
    const u32 (*c1s)[14][20], u16* dst,
    const u32* __restrict__ w2g, const float bv, const int co, const int y)
{
    float acc[28];
    #pragma unroll
    for (int x = 0; x < 28; ++x) acc[x] = bv;
    const int a0 = (y + 1) & 1;
    for (int aa = 0; aa < 2; ++aa) {
        const int a = a0 + 2 * aa;
        const int iy = (y + 1 - a) >> 1;
        if ((unsigned)iy < 14u) {
            #pragma unroll 2
            for (int cip = 0; cip < 8; ++cip) {
                u32 rr[14];
                *(uint4*)&rr[0]  = *(const uint4*)&c1s[cip][iy][0];
                *(uint4*)&rr[4]  = *(const uint4*)&c1s[cip][iy][4];
                *(uint4*)&rr[8]  = *(const uint4*)&c1s[cip][iy][8];
                *(uint2*)&rr[12] = *(const uint2*)&c1s[cip][iy][12];
                const uint4 wq = *(const uint4*)(w2g + ((cip * 4 + a) * 8 + co) * 4);
                const u32 wv[4] = {wq.x, wq.y, wq.z, wq.w};
                #pragma unroll
                for (int x = 0; x < 28; ++x) {
                    const int c0v = (x + 1) & 1;
                    const int ix0 = (x + 1 - c0v) >> 1;
                    if (ix0 < 14) acc[x] = dot2(rr[ix0],     wv[c0v],     acc[x]);
                    if (ix0 >= 1) acc[x] = dot2(rr[ix0 - 1], wv[c0v + 2], acc[x]);
                }
            }
        }
    }
    #pragma unroll
    for (int x = 0; x < 28; ++x) dst[2 * (1 + x)] = f16b(lrelu(acc[x]));
}

// ---------------------------------------------------------------------------
// Kernel 3: all three transposed convs, ONE sample per block (gen-sorted via
// wsi). c2s zero-padded columns (stride 30) -> conv3 vec reads.
// LDS: c1s 8960 + c2s 13440 (aliases dead h2s 3584) = 22.4 KB.
// ---------------------------------------------------------------------------
__global__ __launch_bounds__(256, 6) void conv_kernel(
    const int* __restrict__ g_idx, const int* __restrict__ wsi,
    const u32* __restrict__ wpk1, const float* __restrict__ cb1,
    const u32* __restrict__ wpk2, const float* __restrict__ cb2,
    const u32* __restrict__ wpk3, const float* __restrict__ cb3,
    const u16* __restrict__ h2g, float* __restrict__ out)
{
    __shared__ __align__(16) char smem[8960 + 13440];
    u32 (*c1s)[14][20] = (u32 (*)[14][20])smem;              // [8cip][14][20] 8960 B
    u32 (*h2s)[7][8]   = (u32 (*)[7][8])(smem + 8960);       // [16cip][7][8] 3584 B
    u32 (*c2s)[28][30] = (u32 (*)[28][30])(smem + 8960);     // [4cip][28][30] aliases h2s
    __shared__ u32 w3s[36];

    const int tid = threadIdx.x;
    const int b = wsi[16 + blockIdx.x];
    if (b < 0) return;
    const int g = g_idx[b];
    const u32* w1g = wpk1 + g * 4096;
    const u32* w2g = wpk2 + g * 1024;
    const float* cb1g = cb1 + g * 16;
    const float* cb2g = cb2 + g * 8;
    const float  cb3v = cb3[g];

    // stage h2 (f16 bits straight from fc2) into ci-paired layout
    if (tid < 224) {
        const uint4 qv = ((const uint4*)(h2g + (size_t)b * H2_ELEMS))[tid];
        const int ci = tid / 7, yq = tid % 7;
        u16* dst = (u16*)&h2s[ci >> 1][yq][0] + (ci & 1);
        const u32 w[4] = {qv.x, qv.y, qv.z, qv.w};
        #pragma unroll
        for (int j = 0; j < 4; ++j) {
            dst[4 * j]     = (u16)(w[j] & 0xffffu);
            dst[4 * j + 2] = (u16)(w[j] >> 16);
        }
    }
    if (tid < 36) w3s[tid] = wpk3[g * 36 + tid];
    __syncthreads();

    // conv1: [32,7,7] -> [16,14,14], k=4, s=2, ci-pairs via dot2
    if (tid < 224) {
        const int co = tid / 14, y = tid % 14;
        const float bv = cb1g[co];
        float acc[14];
        #pragma unroll
        for (int x = 0; x < 14; ++x) acc[x] = bv;
        const int a0 = (y + 1) & 1;
        for (int aa = 0; aa < 2; ++aa) {
            const int a = a0 + 2 * aa;
            const int iy = (y + 1 - a) >> 1;
            if ((unsigned)iy < 7u) {
                #pragma unroll 2
                for (int cip = 0; cip < 16; ++cip) {
                    u32 rr[8];
                    *(uint4*)&rr[0] = *(const uint4*)&h2s[cip][iy][0];
                    *(uint4*)&rr[4] = *(const uint4*)&h2s[cip][iy][4];
                    const uint4 wq = *(const uint4*)(w1g + ((cip * 4 + a) * 16 + co) * 4);
                    const u32 wv[4] = {wq.x, wq.y, wq.z, wq.w};
                    #pragma unroll
                    for (int x = 0; x < 14; ++x) {
                        const int c0v = (x + 1) & 1;
                        const int ix0 = (x + 1 - c0v) >> 1;
                        if (ix0 < 7)  acc[x] = dot2(rr[ix0],     wv[c0v],     acc[x]);
                        if (ix0 >= 1) acc[x] = dot2(rr[ix0 - 1], wv[c0v + 2], acc[x]);
                    }
                }
            }
        }
        u16* dst = (u16*)&c1s[co >> 1][y][0] + (co & 1);
        #pragma unroll
        for (int x = 0; x < 14; ++x) dst[2 * x] = f16b(lrelu(acc[x]));
    }
    __syncthreads();   // h2s dead; c2s may be written

    // conv2: [16,14,14] -> [8,28,28] into padded c2s; also zero pad columns.
    // Pad words (0 and 29) and data words (1..28) are disjoint: no race.
    if (tid < 224) {
        const int zc = tid / 56, zr = tid % 56;
        c2s[zc][zr % 28][(zr < 28) ? 0 : 29] = 0u;
        const int co = tid / 28, y = tid % 28;
        const float bv = cb2g[co];
        u16* dst = (u16*)&c2s[co >> 1][y][0] + (co & 1);
        conv2p_full(c1s, dst, w2g, bv, co, y);
    }
    __syncthreads();

    // conv3: [8,28,28] -> [1,28,28], k=3 s=1; padded columns -> vec reads
    if (tid < 196) {
        const int y = tid / 7, qq = tid % 7;
        const int xb = qq * 4;
        float acc[4] = {cb3v, cb3v, cb3v, cb3v};
        #pragma unroll 2
        for (int cip = 0; cip < 4; ++cip) {
            u32 wp[9];
            #pragma unroll
            for (int j = 0; j < 9; ++j) wp[j] = w3s[cip * 9 + j];
            #pragma unroll
            for (int a = 0; a < 3; ++a) {
                const int iy = y + 1 - a;
                if ((unsigned)iy < 28u) {
                    u32 rr[6];
                    *(uint2*)&rr[0] = *(const uint2*)&c2s[cip][iy][xb];
                    *(uint2*)&rr[2] = *(const uint2*)&c2s[cip][iy][xb + 2];
                    *(uint2*)&rr[4] = *(const uint2*)&c2s[cip][iy][xb + 4];
                    #pragma unroll
                    for (int xx = 0; xx < 4; ++xx)
                        #pragma unroll
                        for (int c = 0; c < 3; ++c)
                            acc[xx] = dot2(rr[xx + 2 - c], wp[a * 3 + c], acc[xx]);
                }
            }
        }
        float* op = out + (size_t)b * 784 + y * 28 + xb;
        #pragma unroll
        for (int xx = 0; xx < 4; ++xx) op[xx] = fast_tanh(acc[xx]);
    }
}

extern "C" void kernel_launch(void* const* d_in, const int* in_sizes, int n_in,
                              void* d_out, int out_size, void* d_ws, size_t ws_size,
                              hipStream_t stream) {
    const float* z   = (const float*)d_in[0];
    const int*   gi  = (const int*)d_in[1];
    const float* W1  = (const float*)d_in[2];
    const float* b1  = (const float*)d_in[3];
    const float* W2  = (const float*)d_in[4];
    const float* b2  = (const float*)d_in[5];
    const float* cw1 = (const float*)d_in[6];
    const float* cb1 = (const float*)d_in[7];
    const float* cw2 = (const float*)d_in[8];
    const float* cb2 = (const float*)d_in[9];
    const float* cw3 = (const float*)d_in[10];
    const float* cb3 = (const float*)d_in[11];
    int*      wsi = (int*)d_ws;
    float*    h1g = (float*)((char*)d_ws + WS_H1_OFF);
    u16*      h2g = (u16*)((char*)d_ws + WS_H2_OFF);
    _Float16* w2t = (_Float16*)((char*)d_ws + WS_W2T_OFF);
    u32*      wpk1 = (u32*)((char*)d_ws + WS_WPK1_OFF);
    u32*      wpk2 = (u32*)((char*)d_ws + WS_WPK2_OFF);
    u32*      wpk3 = (u32*)((char*)d_ws + WS_WPK3_OFF);

    prep_kernel<<<NB_PREP + NGEN + 1, 256, 0, stream>>>(z, gi, W1, b1, W2, wsi,
                                                        h1g, w2t, cw1, cw2, cw3,
                                                        wpk1, wpk2, wpk3);
    fc2_kernel<<<MAXG * NCT, 256, 0, stream>>>(gi, w2t, b2, wsi, h1g, h2g);
    conv_kernel<<<MAXG * GRPS, 256, 0, stream>>>(gi, wsi, wpk1, cb1, wpk2, cb2,
                                                 wpk3, cb3, h2g, (float*)d_out);
}

// Round 7
// 160.601 us; speedup vs baseline: 1.0653x; 1.0653x over previous
//
#include <hip/hip_runtime.h>
#include <cstdint>
#include <cstddef>

#define BATCH 2048
#define NZ 128
#define NGEN 8
#define GRPS 32                 // samples per group (same generator)
#define MAXG 72                 // max padded groups
#define NCT 7                   // fc2 col tiles of 256 (6 full + tail 32)
#define H2_ELEMS 1792           // 32*7*8 (x padded 7->8) per sample, f16
#define WS_H1_OFF 16384                                  // h1: 72*8192 fp32
#define WS_H2_OFF (16384 + MAXG * 8192 * 4)              // 2375680
#define WS_W2T_OFF (WS_H2_OFF + BATCH * H2_ELEMS * 2)    // 9715712
#define W2T_GSTRIDE (1568 * 256)                         // fp16 elems per gen
#define NB_W2T (NGEN * 49)                               // 392
#define NB_PREP (NB_W2T + MAXG * 4)                      // 680
// packed f16x2 conv weights (pairs over input channel), per generator:
//   wpk1[g][cip16][a4][co16][c4], wpk2[g][cip8][a4][co8][c4], wpk3[g][cip4][9]
#define WS_WPK1_OFF (WS_W2T_OFF + NGEN * W2T_GSTRIDE * 2)  // 16138240 (16B aligned)
#define WS_WPK2_OFF (WS_WPK1_OFF + NGEN * 4096 * 4)
#define WS_WPK3_OFF (WS_WPK2_OFF + NGEN * 1024 * 4)
#define PS 304                  // fc2 epilogue LDS row stride (u16); max span+slack 300

typedef unsigned int u32;
typedef unsigned short u16;
typedef unsigned long long u64;
typedef _Float16 f16x8 __attribute__((ext_vector_type(8)));
typedef _Float16 f16x4 __attribute__((ext_vector_type(4)));
typedef _Float16 f16x2 __attribute__((ext_vector_type(2)));
typedef float f32x4 __attribute__((ext_vector_type(4)));

__device__ __forceinline__ float lrelu(float x) { return fmaxf(x, 0.2f * x); }
__device__ __forceinline__ u16 f16b(float f) {
    _Float16 h = (_Float16)f;
    return __builtin_bit_cast(u16, h);
}
__device__ __forceinline__ u32 pk2(float a, float b) {
    f16x2 v; v[0] = (_Float16)a; v[1] = (_Float16)b;
    return __builtin_bit_cast(u32, v);
}
// 2-wide f16 dot with f32 accumulate: v_dot2_f32_f16 (2 MACs/instr, full rate)
__device__ __forceinline__ float dot2(u32 a, u32 b, float c) {
#if __has_builtin(__builtin_amdgcn_fdot2)
    return __builtin_amdgcn_fdot2(__builtin_bit_cast(f16x2, a),
                                  __builtin_bit_cast(f16x2, b), c, false);
#else
    float d;
    asm("v_dot2_f32_f16 %0, %1, %2, %3" : "=v"(d) : "v"(a), "v"(b), "v"(c));
    return d;
#endif
}
__device__ __forceinline__ float fast_tanh(float x) {
    x = fminf(fmaxf(x, -9.f), 9.f);
    const float e = __expf(2.f * x);
    return (e - 1.f) / (e + 1.f);
}
// h2 storage offset for fc2 column n (strictly monotone in n)
__device__ __forceinline__ int h2off(int n) {
    const int ci = n / 49, rm = n % 49;
    return ci * 56 + (rm / 7) * 8 + (rm % 7);
}

// ---------------------------------------------------------------------------
// Kernel 1: prep. Roles by blockIdx:
//   [0, NB_W2T)            : W2 transpose -> W2T f16
//   [NB_W2T, NB_PREP)      : grouped FC1 (locally recomputes binning)
//   [NB_PREP, NB_PREP+NGEN): conv-weight f16x2 packing
//   NB_PREP+NGEN           : bin publisher (writes wsi for fc2/conv)
// ---------------------------------------------------------------------------
__global__ __launch_bounds__(256) void prep_kernel(
    const float* __restrict__ z, const int* __restrict__ g_idx,
    const float* __restrict__ W1, const float* __restrict__ b1,
    const float* __restrict__ W2, int* __restrict__ wsi,
    float* __restrict__ h1g, _Float16* __restrict__ W2T,
    const float* __restrict__ cw1, const float* __restrict__ cw2,
    const float* __restrict__ cw3,
    u32* __restrict__ wpk1, u32* __restrict__ wpk2, u32* __restrict__ wpk3)
{
    __shared__ __align__(16) char pmem[16896];   // roles alias this region

    const int tid = threadIdx.x;
    const int bx = blockIdx.x;

    if (bx < NB_W2T) {
        // ---- W2 transpose role: W2[g][k256][n1568] fp32 -> W2T[g][n][k] fp16
        _Float16 (*t)[264] = (_Float16 (*)[264])pmem;   // 16.5 KB
        const int g = bx / 49;
        const int n0 = (bx % 49) * 32;
        const float* src = W2 + (size_t)g * 256 * 1568;
        const int nl = tid & 31, kh = tid >> 5;
        #pragma unroll 8
        for (int p = 0; p < 32; ++p) {
            const int k = p * 8 + kh;
            t[nl][k] = (_Float16)src[(size_t)k * 1568 + n0 + nl];
        }
        __syncthreads();
        _Float16* dst = W2T + (size_t)g * W2T_GSTRIDE + (size_t)n0 * 256;
        #pragma unroll
        for (int ii = 0; ii < 4; ++ii) {
            const int i = tid + 256 * ii;           // 1024 chunks of 16B
            const int n = i >> 5, kc = i & 31;
            *(uint4*)(dst + (size_t)n * 256 + kc * 8) = *(const uint4*)&t[n][kc * 8];
        }
        return;
    }

    if (bx >= NB_PREP && bx < NB_PREP + NGEN) {
        // ---- conv-weight packing role: pair input channels into f16x2 ----
        const int g = bx - NB_PREP;
        const float* c1p = cw1 + g * 8192;             // [32ci][16co][4][4]
        u32* o1 = wpk1 + g * 4096;
        for (int i = tid; i < 4096; i += 256) {
            const int cip = i >> 8, a = (i >> 6) & 3, co = (i >> 2) & 15, c = i & 3;
            const float* s = c1p + cip * 512 + co * 16 + a * 4 + c;
            o1[i] = pk2(s[0], s[256]);
        }
        const float* c2p = cw2 + g * 2048;             // [16ci][8co][4][4]
        u32* o2 = wpk2 + g * 1024;
        for (int i = tid; i < 1024; i += 256) {
            const int cip = i >> 7, a = (i >> 5) & 3, co = (i >> 2) & 7, c = i & 3;
            const float* s = c2p + cip * 256 + co * 16 + a * 4 + c;
            o2[i] = pk2(s[0], s[128]);
        }
        if (tid < 36) {                                // [8ci][1co][3][3]
            const int cip = tid / 9, r = tid % 9;
            const float* s = cw3 + g * 72 + cip * 18 + r;
            wpk3[g * 36 + tid] = pk2(s[0], s[9]);
        }
        return;
    }

    // ---- local binning (shared by fc1 role and bin-publisher role) ----
    u16* rank       = (u16*)pmem;                       // [2048] 4096 B
    int (*wcnt)[NGEN]  = (int (*)[NGEN])(pmem + 4096);  // [4][8]
    int (*wboff)[NGEN] = (int (*)[NGEN])(pmem + 4224);  // [4][8]
    int* pbase      = (int*)(pmem + 4352);              // [9]
    const int w = tid >> 6, lane = tid & 63;
    if (tid < 4 * NGEN) wcnt[tid >> 3][tid & 7] = 0;
    __syncthreads();
    const u64 lt = ((u64)1 << lane) - 1;
    #pragma unroll
    for (int r = 0; r < 8; ++r) {
        const int b = r * 256 + tid;
        const int gg = g_idx[b];
        u64 m[NGEN];
        #pragma unroll
        for (int k = 0; k < NGEN; ++k) m[k] = __ballot(gg == k);
        rank[b] = (u16)((int)__popcll(m[gg] & lt) + wcnt[w][gg]);
        if (lane < NGEN) wcnt[w][lane] += (int)__popcll(m[lane]);
    }
    __syncthreads();
    if (tid == 0) {
        int acc = 0;
        for (int g = 0; g < NGEN; ++g) {
            pbase[g] = acc;
            const int tot = wcnt[0][g] + wcnt[1][g] + wcnt[2][g] + wcnt[3][g];
            acc += ((tot + GRPS - 1) / GRPS) * GRPS;
        }
        pbase[NGEN] = acc;
    }
    __syncthreads();
    if (tid < 32) {
        const int ww = tid >> 3, g = tid & 7;
        int off = pbase[g];
        for (int w2 = 0; w2 < ww; ++w2) off += wcnt[w2][g];
        wboff[ww][g] = off;
    }
    __syncthreads();

    if (bx >= NB_PREP + NGEN) {
        // ---- bin-publisher role: write wsi for fc2/conv ----
        if (tid == 0) wsi[0] = pbase[NGEN];
        for (int i = tid; i < MAXG * GRPS; i += 256) wsi[16 + i] = -1;
        __syncthreads();
        #pragma unroll
        for (int r = 0; r < 8; ++r) {
            const int b = r * 256 + tid;
            const int gg = g_idx[b];
            wsi[16 + wboff[w][gg] + (int)rank[b]] = b;
        }
        return;
    }

    // ---- FC1 role (grouped): (group, 8-sample slice) ----
    const int bx2 = bx - NB_W2T;
    const int grp = bx2 >> 2;
    const int s0 = (bx2 & 3) * 8;
    if (grp * GRPS >= pbase[NGEN]) return;

    int gsel = 0;
    #pragma unroll
    for (int g = 1; g < NGEN; ++g) if (grp * GRPS >= pbase[g]) gsel = g;

    int* sb = (int*)(pmem + 4400);                     // [8]
    float (*zst)[12] = (float (*)[12])(pmem + 4608);   // [128][12] 6144 B
    if (tid < 8) sb[tid] = -1;
    __syncthreads();
    const int base = grp * GRPS + s0;
    #pragma unroll
    for (int r = 0; r < 8; ++r) {
        const int b = r * 256 + tid;
        const int gg = g_idx[b];
        const int rel = wboff[w][gg] + (int)rank[b] - base;
        if ((unsigned)rel < 8u) sb[rel] = b;
    }
    __syncthreads();

    const float* W1g = W1 + gsel * (NZ * 256);
    const float* b1g = b1 + gsel * 256;

    {   // stage z: 8 samples x 128 = 256 float4, one per thread
        const int s = tid >> 5, f = tid & 31;
        float4 v = make_float4(0.f, 0.f, 0.f, 0.f);
        if (sb[s] >= 0) v = *(const float4*)(z + (size_t)sb[s] * NZ + 4 * f);
        zst[4 * f + 0][s] = v.x; zst[4 * f + 1][s] = v.y;
        zst[4 * f + 2][s] = v.z; zst[4 * f + 3][s] = v.w;
    }
    __syncthreads();

    const int c = tid;
    float acc[8];
    #pragma unroll
    for (int s = 0; s < 8; ++s) acc[s] = 0.f;
    const float* wp = W1g + c;
    #pragma unroll 4
    for (int k = 0; k < NZ; ++k) {
        const float wv = wp[k * 256];
        float av[8];
        *(float4*)&av[0] = *(const float4*)&zst[k][0];
        *(float4*)&av[4] = *(const float4*)&zst[k][4];
        #pragma unroll
        for (int s = 0; s < 8; ++s) acc[s] += av[s] * wv;
    }
    const float bv = b1g[c];
    float* hp = h1g + (size_t)grp * 8192 + (size_t)s0 * 256 + c;
    #pragma unroll
    for (int s = 0; s < 8; ++s) hp[s * 256] = lrelu(acc[s] + bv);
}

// ---------------------------------------------------------------------------
// Kernel 2: FC2 via fp16 MFMA 16x16x32 — staged A (r5-proven) + WIDE tiles.
// 256 cols per block (NCT=7): A is staged once per 256 cols instead of once
// per 128 (halves redundant A re-staging across tiles; 13->7 stagings/group)
// and block count halves (936->504). Math order per column unchanged ->
// bit-identical results. pst span <= 293 (+7 align slack) -> PS=304.
// ---------------------------------------------------------------------------
__global__ __launch_bounds__(256) void fc2_kernel(
    const int* __restrict__ g_idx,
    const _Float16* __restrict__ W2T, const float* __restrict__ b2,
    const int* __restrict__ wsi, const float* __restrict__ h1g,
    u16* __restrict__ h2g)
{
    __shared__ __align__(16) char afsm[GRPS * PS * 2];   // 19456B; afrag uses 16384
    _Float16* afrag = (_Float16*)afsm;
    __shared__ int sb[GRPS];
    __shared__ int sG;

    const int tid = threadIdx.x;
    const int grp = blockIdx.x / NCT;
    const int tile = blockIdx.x % NCT;
    if (grp * GRPS >= wsi[0]) return;   // whole block uniform: before barriers

    if (tid == 0) sG = g_idx[wsi[16 + grp * GRPS]];
    if (tid < GRPS) sb[tid] = wsi[16 + grp * GRPS + tid];
    __syncthreads();
    const _Float16* W2Tg = W2T + (size_t)sG * W2T_GSTRIDE;
    const float* b2g = b2 + sG * 1568;

    // ---- stage A fragments (single f16), conflict-free stores ----
    {
        const float4* h1p4 = (const float4*)(h1g + (size_t)grp * 8192);
        #pragma unroll
        for (int i = 0; i < 8; ++i) {
            const int u = tid + 256 * i;
            const int j4 = u & 1;                  // j base = 4*j4
            const int ln = (u >> 1) & 63;
            const int kq = (u >> 7) & 7;
            const int mt = (u >> 10) & 1;
            const int s = mt * 16 + (ln & 15);
            const float4 v = h1p4[s * 64 + kq * 8 + ((ln >> 4) << 1) + j4];
            f16x4 hi;
            hi[0] = (_Float16)v.x; hi[1] = (_Float16)v.y;
            hi[2] = (_Float16)v.z; hi[3] = (_Float16)v.w;
            const int bh = ((mt * 8 + kq) * 64 + ln) * 8 + 4 * j4;
            *(f16x4*)&afrag[bh] = hi;   // addr = base + 8*u bytes: conflict-free
        }
    }
    __syncthreads();

    const int wave = tid >> 6;
    const int lane = tid & 63;
    const int q = lane >> 4;
    const int nl = lane & 15;
    // wave covers 64 cols: nb(nt) = tile*256 + wave*64 + nt*16, nt=0..3
    const int nbw = tile * 256 + wave * 64;

    f32x4 accA[4], accB[4];
    #pragma unroll
    for (int nt = 0; nt < 4; ++nt) {
        accA[nt] = (f32x4){0.f, 0.f, 0.f, 0.f};
        accB[nt] = accA[nt];
    }
    #pragma unroll
    for (int nt = 0; nt < 4; ++nt) {
        const int nb = nbw + nt * 16;
        if (nb < 1568) {
            const _Float16* bp = W2Tg + (size_t)(nb + nl) * 256 + q * 8;
            #pragma unroll
            for (int kq = 0; kq < 8; ++kq) {
                const f16x8 b = *(const f16x8*)(bp + kq * 32);
                const f16x8 a0 = *(const f16x8*)&afrag[((0 * 8 + kq) * 64 + lane) * 8];
                const f16x8 a1 = *(const f16x8*)&afrag[((1 * 8 + kq) * 64 + lane) * 8];
                accA[nt] = __builtin_amdgcn_mfma_f32_16x16x32_f16(a0, b, accA[nt], 0, 0, 0);
                accB[nt] = __builtin_amdgcn_mfma_f32_16x16x32_f16(a1, b, accB[nt], 0, 0, 0);
            }
        }
    }
    __syncthreads();               // all afrag reads done; reuse as pst

    u16* pst = (u16*)afsm;         // [GRPS][PS] indexed manually
    const int nstart = tile * 256;
    const int nend = (nstart + 256 < 1568) ? nstart + 256 : 1568;
    const int offLo = h2off(nstart), offHi = h2off(nend - 1);
    const int lo8 = offLo & ~7;

    #pragma unroll
    for (int nt = 0; nt < 4; ++nt) {
        const int nb = nbw + nt * 16;
        if (nb < 1568) {
            const int n = nb + nl;
            const float bias = b2g[n];
            u16* pp = pst + (h2off(n) - lo8);
            #pragma unroll
            for (int reg = 0; reg < 4; ++reg) {
                pp[(q * 4 + reg) * PS]      = f16b(lrelu(accA[nt][reg] + bias));
                pp[(16 + q * 4 + reg) * PS] = f16b(lrelu(accB[nt][reg] + bias));
            }
        }
    }
    __syncthreads();

    // ---- coalesced copy-out: 8 threads per sample ----
    {
        const int s = tid >> 3, p = tid & 7;
        const int bb = sb[s];
        if (bb >= 0) {
            u16* row = h2g + (size_t)bb * H2_ELEMS;
            const u16* ps = pst + s * PS - lo8;        // index by off directly
            const int c0 = (offLo + 7) & ~7;           // first aligned chunk
            const int c1 = (offHi + 1) & ~7;           // end of aligned chunks
            for (int o = offLo + p; o < c0 && o <= offHi; o += 8) row[o] = ps[o];
            const int t0 = (c1 > offLo) ? c1 : offLo;
            for (int o = t0 + p; o <= offHi; o += 8) row[o] = ps[o];
            for (int c = c0 + p * 8; c + 8 <= c1; c += 64)
                *(uint4*)(row + c) = *(const uint4*)(ps + c);
        }
    }
}

// ---------------------------------------------------------------------------
// conv2 merged full-width pass: rr loaded ONCE per (cip,a), acc[28].
// Output written into zero-padded c2s at column 1+x (stride 30).
// ---------------------------------------------------------------------------
__device__ __forceinline__ void conv2p_full(
    const u32 (*c1s)[14][20], u16* dst,
    const u32* __restrict__ w2g, const float bv, const int co, const int y)
{
    float acc[28];
    #pragma unroll
    for (int x = 0; x < 28; ++x) acc[x] = bv;
    const int a0 = (y + 1) & 1;
    for (int aa = 0; aa < 2; ++aa) {
        const int a = a0 + 2 * aa;
        const int iy = (y + 1 - a) >> 1;
        if ((unsigned)iy < 14u) {
            #pragma unroll 2
            for (int cip = 0; cip < 8; ++cip) {
                u32 rr[14];
                *(uint4*)&rr[0]  = *(const uint4*)&c1s[cip][iy][0];
                *(uint4*)&rr[4]  = *(const uint4*)&c1s[cip][iy][4];
                *(uint4*)&rr[8]  = *(const uint4*)&c1s[cip][iy][8];
                *(uint2*)&rr[12] = *(const uint2*)&c1s[cip][iy][12];
                const uint4 wq = *(const uint4*)(w2g + ((cip * 4 + a) * 8 + co) * 4);
                const u32 wv[4] = {wq.x, wq.y, wq.z, wq.w};
                #pragma unroll
                for (int x = 0; x < 28; ++x) {
                    const int c0v = (x + 1) & 1;
                    const int ix0 = (x + 1 - c0v) >> 1;
                    if (ix0 < 14) acc[x] = dot2(rr[ix0],     wv[c0v],     acc[x]);
                    if (ix0 >= 1) acc[x] = dot2(rr[ix0 - 1], wv[c0v + 2], acc[x]);
                }
            }
        }
    }
    #pragma unroll
    for (int x = 0; x < 28; ++x) dst[2 * (1 + x)] = f16b(lrelu(acc[x]));
}

// ---------------------------------------------------------------------------
// Kernel 3: all three transposed convs, ONE sample per block (gen-sorted via
// wsi). c2s zero-padded columns (stride 30) -> conv3 vec reads.
// LDS: c1s 8960 + c2s 13440 (aliases dead h2s 3584) = 22.4 KB.
// ---------------------------------------------------------------------------
__global__ __launch_bounds__(256, 6) void conv_kernel(
    const int* __restrict__ g_idx, const int* __restrict__ wsi,
    const u32* __restrict__ wpk1, const float* __restrict__ cb1,
    const u32* __restrict__ wpk2, const float* __restrict__ cb2,
    const u32* __restrict__ wpk3, const float* __restrict__ cb3,
    const u16* __restrict__ h2g, float* __restrict__ out)
{
    __shared__ __align__(16) char smem[8960 + 13440];
    u32 (*c1s)[14][20] = (u32 (*)[14][20])smem;              // [8cip][14][20] 8960 B
    u32 (*h2s)[7][8]   = (u32 (*)[7][8])(smem + 8960);       // [16cip][7][8] 3584 B
    u32 (*c2s)[28][30] = (u32 (*)[28][30])(smem + 8960);     // [4cip][28][30] aliases h2s
    __shared__ u32 w3s[36];

    const int tid = threadIdx.x;
    const int b = wsi[16 + blockIdx.x];
    if (b < 0) return;
    const int g = g_idx[b];
    const u32* w1g = wpk1 + g * 4096;
    const u32* w2g = wpk2 + g * 1024;
    const float* cb1g = cb1 + g * 16;
    const float* cb2g = cb2 + g * 8;
    const float  cb3v = cb3[g];

    // stage h2 (f16 bits straight from fc2) into ci-paired layout
    if (tid < 224) {
        const uint4 qv = ((const uint4*)(h2g + (size_t)b * H2_ELEMS))[tid];
        const int ci = tid / 7, yq = tid % 7;
        u16* dst = (u16*)&h2s[ci >> 1][yq][0] + (ci & 1);
        const u32 w[4] = {qv.x, qv.y, qv.z, qv.w};
        #pragma unroll
        for (int j = 0; j < 4; ++j) {
            dst[4 * j]     = (u16)(w[j] & 0xffffu);
            dst[4 * j + 2] = (u16)(w[j] >> 16);
        }
    }
    if (tid < 36) w3s[tid] = wpk3[g * 36 + tid];
    __syncthreads();

    // conv1: [32,7,7] -> [16,14,14], k=4, s=2, ci-pairs via dot2
    if (tid < 224) {
        const int co = tid / 14, y = tid % 14;
        const float bv = cb1g[co];
        float acc[14];
        #pragma unroll
        for (int x = 0; x < 14; ++x) acc[x] = bv;
        const int a0 = (y + 1) & 1;
        for (int aa = 0; aa < 2; ++aa) {
            const int a = a0 + 2 * aa;
            const int iy = (y + 1 - a) >> 1;
            if ((unsigned)iy < 7u) {
                #pragma unroll 2
                for (int cip = 0; cip < 16; ++cip) {
                    u32 rr[8];
                    *(uint4*)&rr[0] = *(const uint4*)&h2s[cip][iy][0];
                    *(uint4*)&rr[4] = *(const uint4*)&h2s[cip][iy][4];
                    const uint4 wq = *(const uint4*)(w1g + ((cip * 4 + a) * 16 + co) * 4);
                    const u32 wv[4] = {wq.x, wq.y, wq.z, wq.w};
                    #pragma unroll
                    for (int x = 0; x < 14; ++x) {
                        const int c0v = (x + 1) & 1;
                        const int ix0 = (x + 1 - c0v) >> 1;
                        if (ix0 < 7)  acc[x] = dot2(rr[ix0],     wv[c0v],     acc[x]);
                        if (ix0 >= 1) acc[x] = dot2(rr[ix0 - 1], wv[c0v + 2], acc[x]);
                    }
                }
            }
        }
        u16* dst = (u16*)&c1s[co >> 1][y][0] + (co & 1);
        #pragma unroll
        for (int x = 0; x < 14; ++x) dst[2 * x] = f16b(lrelu(acc[x]));
    }
    __syncthreads();   // h2s dead; c2s may be written

    // conv2: [16,14,14] -> [8,28,28] into padded c2s; also zero pad columns.
    // Pad words (0 and 29) and data words (1..28) are disjoint: no race.
    if (tid < 224) {
        const int zc = tid / 56, zr = tid % 56;
        c2s[zc][zr % 28][(zr < 28) ? 0 : 29] = 0u;
        const int co = tid / 28, y = tid % 28;
        const float bv = cb2g[co];
        u16* dst = (u16*)&c2s[co >> 1][y][0] + (co & 1);
        conv2p_full(c1s, dst, w2g, bv, co, y);
    }
    __syncthreads();

    // conv3: [8,28,28] -> [1,28,28], k=3 s=1; padded columns -> vec reads
    if (tid < 196) {
        const int y = tid / 7, qq = tid % 7;
        const int xb = qq * 4;
        float acc[4] = {cb3v, cb3v, cb3v, cb3v};
        #pragma unroll 2
        for (int cip = 0; cip < 4; ++cip) {
            u32 wp[9];
            #pragma unroll
            for (int j = 0; j < 9; ++j) wp[j] = w3s[cip * 9 + j];
            #pragma unroll
            for (int a = 0; a < 3; ++a) {
                const int iy = y + 1 - a;
                if ((unsigned)iy < 28u) {
                    u32 rr[6];
                    *(uint2*)&rr[0] = *(const uint2*)&c2s[cip][iy][xb];
                    *(uint2*)&rr[2] = *(const uint2*)&c2s[cip][iy][xb + 2];
                    *(uint2*)&rr[4] = *(const uint2*)&c2s[cip][iy][xb + 4];
                    #pragma unroll
                    for (int xx = 0; xx < 4; ++xx)
                        #pragma unroll
                        for (int c = 0; c < 3; ++c)
                            acc[xx] = dot2(rr[xx + 2 - c], wp[a * 3 + c], acc[xx]);
                }
            }
        }
        float* op = out + (size_t)b * 784 + y * 28 + xb;
        #pragma unroll
        for (int xx = 0; xx < 4; ++xx) op[xx] = fast_tanh(acc[xx]);
    }
}

extern "C" void kernel_launch(void* const* d_in, const int* in_sizes, int n_in,
                              void* d_out, int out_size, void* d_ws, size_t ws_size,
                              hipStream_t stream) {
    const float* z   = (const float*)d_in[0];
    const int*   gi  = (const int*)d_in[1];
    const float* W1  = (const float*)d_in[2];
    const float* b1  = (const float*)d_in[3];
    const float* W2  = (const float*)d_in[4];
    const float* b2  = (const float*)d_in[5];
    const float* cw1 = (const float*)d_in[6];
    const float* cb1 = (const float*)d_in[7];
    const float* cw2 = (const float*)d_in[8];
    const float* cb2 = (const float*)d_in[9];
    const float* cw3 = (const float*)d_in[10];
    const float* cb3 = (const float*)d_in[11];
    int*      wsi = (int*)d_ws;
    float*    h1g = (float*)((char*)d_ws + WS_H1_OFF);
    u16*      h2g = (u16*)((char*)d_ws + WS_H2_OFF);
    _Float16* w2t = (_Float16*)((char*)d_ws + WS_W2T_OFF);
    u32*      wpk1 = (u32*)((char*)d_ws + WS_WPK1_OFF);
    u32*      wpk2 = (u32*)((char*)d_ws + WS_WPK2_OFF);
    u32*      wpk3 = (u32*)((char*)d_ws + WS_WPK3_OFF);

    prep_kernel<<<NB_PREP + NGEN + 1, 256, 0, stream>>>(z, gi, W1, b1, W2, wsi,
                                                        h1g, w2t, cw1, cw2, cw3,
                                                        wpk1, wpk2, wpk3);
    fc2_kernel<<<MAXG * NCT, 256, 0, stream>>>(gi, w2t, b2, wsi, h1g, h2g);
    conv_kernel<<<MAXG * GRPS, 256, 0, stream>>>(gi, wsi, wpk1, cb1, wpk2, cb2,
                                                 wpk3, cb3, h2g, (float*)d_out);
}

// Round 8
// 148.351 us; speedup vs baseline: 1.1533x; 1.0826x over previous
//
#include <hip/hip_runtime.h>
#include <cstdint>
#include <cstddef>

#define BATCH 2048
#define NZ 128
#define NGEN 8
#define GRPS 32                 // samples per group (same generator)
#define MAXG 72                 // max padded groups
#define NCT 7                   // fc2 col tiles of 256 (6 full + tail 32)
#define H2_ELEMS 1792           // 32*7*8 (x padded 7->8) per sample, f16
#define WS_H1_OFF 16384                                  // h1: 72*8192 fp32
#define WS_H2_OFF (16384 + MAXG * 8192 * 4)              // 2375680
#define WS_W2T_OFF (WS_H2_OFF + BATCH * H2_ELEMS * 2)    // 9715712
#define W2T_GSTRIDE (1568 * 256)                         // fp16 elems per gen
#define NB_W2T (NGEN * 49)                               // 392
#define NB_PREP (NB_W2T + MAXG * 4)                      // 680
// conv weights: apk1 = conv1 MFMA A-pack [g][par4][t4][co16][ci32] f16 (16KB/g)
//               wpk2[g][cip8][a4][co8][c4] f16x2, wpk3[g][cip4][9] f16x2
#define WS_WPK1_OFF (WS_W2T_OFF + NGEN * W2T_GSTRIDE * 2)  // 16138240 (16B aligned)
#define WS_WPK2_OFF (WS_WPK1_OFF + NGEN * 8192 * 2)
#define WS_WPK3_OFF (WS_WPK2_OFF + NGEN * 1024 * 4)
#define PS 304                  // fc2 epilogue LDS row stride (u16); max span+slack 300

typedef unsigned int u32;
typedef unsigned short u16;
typedef unsigned long long u64;
typedef _Float16 f16x8 __attribute__((ext_vector_type(8)));
typedef _Float16 f16x4 __attribute__((ext_vector_type(4)));
typedef _Float16 f16x2 __attribute__((ext_vector_type(2)));
typedef float f32x4 __attribute__((ext_vector_type(4)));

__device__ __forceinline__ float lrelu(float x) { return fmaxf(x, 0.2f * x); }
__device__ __forceinline__ u16 f16b(float f) {
    _Float16 h = (_Float16)f;
    return __builtin_bit_cast(u16, h);
}
__device__ __forceinline__ u32 pk2(float a, float b) {
    f16x2 v; v[0] = (_Float16)a; v[1] = (_Float16)b;
    return __builtin_bit_cast(u32, v);
}
// 2-wide f16 dot with f32 accumulate: v_dot2_f32_f16 (2 MACs/instr, full rate)
__device__ __forceinline__ float dot2(u32 a, u32 b, float c) {
#if __has_builtin(__builtin_amdgcn_fdot2)
    return __builtin_amdgcn_fdot2(__builtin_bit_cast(f16x2, a),
                                  __builtin_bit_cast(f16x2, b), c, false);
#else
    float d;
    asm("v_dot2_f32_f16 %0, %1, %2, %3" : "=v"(d) : "v"(a), "v"(b), "v"(c));
    return d;
#endif
}
__device__ __forceinline__ float fast_tanh(float x) {
    x = fminf(fmaxf(x, -9.f), 9.f);
    const float e = __expf(2.f * x);
    return (e - 1.f) / (e + 1.f);
}
// h2 storage offset for fc2 column n (strictly monotone in n)
__device__ __forceinline__ int h2off(int n) {
    const int ci = n / 49, rm = n % 49;
    return ci * 56 + (rm / 7) * 8 + (rm % 7);
}

// ---------------------------------------------------------------------------
// Kernel 1: prep. Roles by blockIdx:
//   [0, NB_W2T)            : W2 transpose -> W2T f16
//   [NB_W2T, NB_PREP)      : grouped FC1 (locally recomputes binning)
//   [NB_PREP, NB_PREP+NGEN): conv-weight packing (apk1 MFMA-pack + wpk2/3)
//   NB_PREP+NGEN           : bin publisher (writes wsi for fc2/conv)
// ---------------------------------------------------------------------------
__global__ __launch_bounds__(256) void prep_kernel(
    const float* __restrict__ z, const int* __restrict__ g_idx,
    const float* __restrict__ W1, const float* __restrict__ b1,
    const float* __restrict__ W2, int* __restrict__ wsi,
    float* __restrict__ h1g, _Float16* __restrict__ W2T,
    const float* __restrict__ cw1, const float* __restrict__ cw2,
    const float* __restrict__ cw3,
    u16* __restrict__ apk1, u32* __restrict__ wpk2, u32* __restrict__ wpk3)
{
    __shared__ __align__(16) char pmem[16896];   // roles alias this region

    const int tid = threadIdx.x;
    const int bx = blockIdx.x;

    if (bx < NB_W2T) {
        // ---- W2 transpose role: W2[g][k256][n1568] fp32 -> W2T[g][n][k] fp16
        _Float16 (*t)[264] = (_Float16 (*)[264])pmem;   // 16.5 KB
        const int g = bx / 49;
        const int n0 = (bx % 49) * 32;
        const float* src = W2 + (size_t)g * 256 * 1568;
        const int nl = tid & 31, kh = tid >> 5;
        #pragma unroll 8
        for (int p = 0; p < 32; ++p) {
            const int k = p * 8 + kh;
            t[nl][k] = (_Float16)src[(size_t)k * 1568 + n0 + nl];
        }
        __syncthreads();
        _Float16* dst = W2T + (size_t)g * W2T_GSTRIDE + (size_t)n0 * 256;
        #pragma unroll
        for (int ii = 0; ii < 4; ++ii) {
            const int i = tid + 256 * ii;           // 1024 chunks of 16B
            const int n = i >> 5, kc = i & 31;
            *(uint4*)(dst + (size_t)n * 256 + kc * 8) = *(const uint4*)&t[n][kc * 8];
        }
        return;
    }

    if (bx >= NB_PREP && bx < NB_PREP + NGEN) {
        // ---- conv-weight packing role ----
        const int g = bx - NB_PREP;
        // conv1 MFMA A-pack: apk1[par(py*2+px)][t][co][ci] f16,
        //   a = 1-py+2*(t>>1), c = 1-px+2*(t&1)  (tap t, shift dy=py-(t>>1)).
        const float* c1p = cw1 + g * 8192;             // [32ci][16co][4][4]
        u16* o1 = apk1 + g * 8192;
        for (int i = tid; i < 8192; i += 256) {
            const int ci = i & 31, co = (i >> 5) & 15, t = (i >> 9) & 3;
            const int px = (i >> 11) & 1, py = (i >> 12) & 1;
            const int a = 1 - py + 2 * (t >> 1);
            const int c = 1 - px + 2 * (t & 1);
            o1[i] = f16b(c1p[ci * 256 + co * 16 + a * 4 + c]);
        }
        const float* c2p = cw2 + g * 2048;             // [16ci][8co][4][4]
        u32* o2 = wpk2 + g * 1024;
        for (int i = tid; i < 1024; i += 256) {
            const int cip = i >> 7, a = (i >> 5) & 3, co = (i >> 2) & 7, c = i & 3;
            const float* s = c2p + cip * 256 + co * 16 + a * 4 + c;
            o2[i] = pk2(s[0], s[128]);
        }
        if (tid < 36) {                                // [8ci][1co][3][3]
            const int cip = tid / 9, r = tid % 9;
            const float* s = cw3 + g * 72 + cip * 18 + r;
            wpk3[g * 36 + tid] = pk2(s[0], s[9]);
        }
        return;
    }

    // ---- local binning (shared by fc1 role and bin-publisher role) ----
    u16* rank       = (u16*)pmem;                       // [2048] 4096 B
    int (*wcnt)[NGEN]  = (int (*)[NGEN])(pmem + 4096);  // [4][8]
    int (*wboff)[NGEN] = (int (*)[NGEN])(pmem + 4224);  // [4][8]
    int* pbase      = (int*)(pmem + 4352);              // [9]
    const int w = tid >> 6, lane = tid & 63;
    if (tid < 4 * NGEN) wcnt[tid >> 3][tid & 7] = 0;
    __syncthreads();
    const u64 lt = ((u64)1 << lane) - 1;
    #pragma unroll
    for (int r = 0; r < 8; ++r) {
        const int b = r * 256 + tid;
        const int gg = g_idx[b];
        u64 m[NGEN];
        #pragma unroll
        for (int k = 0; k < NGEN; ++k) m[k] = __ballot(gg == k);
        rank[b] = (u16)((int)__popcll(m[gg] & lt) + wcnt[w][gg]);
        if (lane < NGEN) wcnt[w][lane] += (int)__popcll(m[lane]);
    }
    __syncthreads();
    if (tid == 0) {
        int acc = 0;
        for (int g = 0; g < NGEN; ++g) {
            pbase[g] = acc;
            const int tot = wcnt[0][g] + wcnt[1][g] + wcnt[2][g] + wcnt[3][g];
            acc += ((tot + GRPS - 1) / GRPS) * GRPS;
        }
        pbase[NGEN] = acc;
    }
    __syncthreads();
    if (tid < 32) {
        const int ww = tid >> 3, g = tid & 7;
        int off = pbase[g];
        for (int w2 = 0; w2 < ww; ++w2) off += wcnt[w2][g];
        wboff[ww][g] = off;
    }
    __syncthreads();

    if (bx >= NB_PREP + NGEN) {
        // ---- bin-publisher role: write wsi for fc2/conv ----
        if (tid == 0) wsi[0] = pbase[NGEN];
        for (int i = tid; i < MAXG * GRPS; i += 256) wsi[16 + i] = -1;
        __syncthreads();
        #pragma unroll
        for (int r = 0; r < 8; ++r) {
            const int b = r * 256 + tid;
            const int gg = g_idx[b];
            wsi[16 + wboff[w][gg] + (int)rank[b]] = b;
        }
        return;
    }

    // ---- FC1 role (grouped): (group, 8-sample slice) ----
    const int bx2 = bx - NB_W2T;
    const int grp = bx2 >> 2;
    const int s0 = (bx2 & 3) * 8;
    if (grp * GRPS >= pbase[NGEN]) return;

    int gsel = 0;
    #pragma unroll
    for (int g = 1; g < NGEN; ++g) if (grp * GRPS >= pbase[g]) gsel = g;

    int* sb = (int*)(pmem + 4400);                     // [8]
    float (*zst)[12] = (float (*)[12])(pmem + 4608);   // [128][12] 6144 B
    if (tid < 8) sb[tid] = -1;
    __syncthreads();
    const int base = grp * GRPS + s0;
    #pragma unroll
    for (int r = 0; r < 8; ++r) {
        const int b = r * 256 + tid;
        const int gg = g_idx[b];
        const int rel = wboff[w][gg] + (int)rank[b] - base;
        if ((unsigned)rel < 8u) sb[rel] = b;
    }
    __syncthreads();

    const float* W1g = W1 + gsel * (NZ * 256);
    const float* b1g = b1 + gsel * 256;

    {   // stage z: 8 samples x 128 = 256 float4, one per thread
        const int s = tid >> 5, f = tid & 31;
        float4 v = make_float4(0.f, 0.f, 0.f, 0.f);
        if (sb[s] >= 0) v = *(const float4*)(z + (size_t)sb[s] * NZ + 4 * f);
        zst[4 * f + 0][s] = v.x; zst[4 * f + 1][s] = v.y;
        zst[4 * f + 2][s] = v.z; zst[4 * f + 3][s] = v.w;
    }
    __syncthreads();

    const int c = tid;
    float acc[8];
    #pragma unroll
    for (int s = 0; s < 8; ++s) acc[s] = 0.f;
    const float* wp = W1g + c;
    #pragma unroll 4
    for (int k = 0; k < NZ; ++k) {
        const float wv = wp[k * 256];
        float av[8];
        *(float4*)&av[0] = *(const float4*)&zst[k][0];
        *(float4*)&av[4] = *(const float4*)&zst[k][4];
        #pragma unroll
        for (int s = 0; s < 8; ++s) acc[s] += av[s] * wv;
    }
    const float bv = b1g[c];
    float* hp = h1g + (size_t)grp * 8192 + (size_t)s0 * 256 + c;
    #pragma unroll
    for (int s = 0; s < 8; ++s) hp[s * 256] = lrelu(acc[s] + bv);
}

// ---------------------------------------------------------------------------
// Kernel 2: FC2 via fp16 MFMA 16x16x32 — staged A + wide 256-col tiles.
// ---------------------------------------------------------------------------
__global__ __launch_bounds__(256) void fc2_kernel(
    const int* __restrict__ g_idx,
    const _Float16* __restrict__ W2T, const float* __restrict__ b2,
    const int* __restrict__ wsi, const float* __restrict__ h1g,
    u16* __restrict__ h2g)
{
    __shared__ __align__(16) char afsm[GRPS * PS * 2];   // 19456B; afrag uses 16384
    _Float16* afrag = (_Float16*)afsm;
    __shared__ int sb[GRPS];
    __shared__ int sG;

    const int tid = threadIdx.x;
    const int grp = blockIdx.x / NCT;
    const int tile = blockIdx.x % NCT;
    if (grp * GRPS >= wsi[0]) return;   // whole block uniform: before barriers

    if (tid == 0) sG = g_idx[wsi[16 + grp * GRPS]];
    if (tid < GRPS) sb[tid] = wsi[16 + grp * GRPS + tid];
    __syncthreads();
    const _Float16* W2Tg = W2T + (size_t)sG * W2T_GSTRIDE;
    const float* b2g = b2 + sG * 1568;

    // ---- stage A fragments (single f16), conflict-free stores ----
    {
        const float4* h1p4 = (const float4*)(h1g + (size_t)grp * 8192);
        #pragma unroll
        for (int i = 0; i < 8; ++i) {
            const int u = tid + 256 * i;
            const int j4 = u & 1;                  // j base = 4*j4
            const int ln = (u >> 1) & 63;
            const int kq = (u >> 7) & 7;
            const int mt = (u >> 10) & 1;
            const int s = mt * 16 + (ln & 15);
            const float4 v = h1p4[s * 64 + kq * 8 + ((ln >> 4) << 1) + j4];
            f16x4 hi;
            hi[0] = (_Float16)v.x; hi[1] = (_Float16)v.y;
            hi[2] = (_Float16)v.z; hi[3] = (_Float16)v.w;
            const int bh = ((mt * 8 + kq) * 64 + ln) * 8 + 4 * j4;
            *(f16x4*)&afrag[bh] = hi;   // addr = base + 8*u bytes: conflict-free
        }
    }
    __syncthreads();

    const int wave = tid >> 6;
    const int lane = tid & 63;
    const int q = lane >> 4;
    const int nl = lane & 15;
    // wave covers 64 cols: nb(nt) = tile*256 + wave*64 + nt*16, nt=0..3
    const int nbw = tile * 256 + wave * 64;

    f32x4 accA[4], accB[4];
    #pragma unroll
    for (int nt = 0; nt < 4; ++nt) {
        accA[nt] = (f32x4){0.f, 0.f, 0.f, 0.f};
        accB[nt] = accA[nt];
    }
    #pragma unroll
    for (int nt = 0; nt < 4; ++nt) {
        const int nb = nbw + nt * 16;
        if (nb < 1568) {
            const _Float16* bp = W2Tg + (size_t)(nb + nl) * 256 + q * 8;
            #pragma unroll
            for (int kq = 0; kq < 8; ++kq) {
                const f16x8 b = *(const f16x8*)(bp + kq * 32);
                const f16x8 a0 = *(const f16x8*)&afrag[((0 * 8 + kq) * 64 + lane) * 8];
                const f16x8 a1 = *(const f16x8*)&afrag[((1 * 8 + kq) * 64 + lane) * 8];
                accA[nt] = __builtin_amdgcn_mfma_f32_16x16x32_f16(a0, b, accA[nt], 0, 0, 0);
                accB[nt] = __builtin_amdgcn_mfma_f32_16x16x32_f16(a1, b, accB[nt], 0, 0, 0);
            }
        }
    }
    __syncthreads();               // all afrag reads done; reuse as pst

    u16* pst = (u16*)afsm;         // [GRPS][PS] indexed manually
    const int nstart = tile * 256;
    const int nend = (nstart + 256 < 1568) ? nstart + 256 : 1568;
    const int offLo = h2off(nstart), offHi = h2off(nend - 1);
    const int lo8 = offLo & ~7;

    #pragma unroll
    for (int nt = 0; nt < 4; ++nt) {
        const int nb = nbw + nt * 16;
        if (nb < 1568) {
            const int n = nb + nl;
            const float bias = b2g[n];
            u16* pp = pst + (h2off(n) - lo8);
            #pragma unroll
            for (int reg = 0; reg < 4; ++reg) {
                pp[(q * 4 + reg) * PS]      = f16b(lrelu(accA[nt][reg] + bias));
                pp[(16 + q * 4 + reg) * PS] = f16b(lrelu(accB[nt][reg] + bias));
            }
        }
    }
    __syncthreads();

    // ---- coalesced copy-out: 8 threads per sample ----
    {
        const int s = tid >> 3, p = tid & 7;
        const int bb = sb[s];
        if (bb >= 0) {
            u16* row = h2g + (size_t)bb * H2_ELEMS;
            const u16* ps = pst + s * PS - lo8;        // index by off directly
            const int c0 = (offLo + 7) & ~7;           // first aligned chunk
            const int c1 = (offHi + 1) & ~7;           // end of aligned chunks
            for (int o = offLo + p; o < c0 && o <= offHi; o += 8) row[o] = ps[o];
            const int t0 = (c1 > offLo) ? c1 : offLo;
            for (int o = t0 + p; o <= offHi; o += 8) row[o] = ps[o];
            for (int c = c0 + p * 8; c + 8 <= c1; c += 64)
                *(uint4*)(row + c) = *(const uint4*)(ps + c);
        }
    }
}

// ---------------------------------------------------------------------------
// conv2 merged full-width pass: rr loaded ONCE per (cip,a), acc[28].
// Output written into zero-padded c2s at column 1+x (stride 30).
// ---------------------------------------------------------------------------
__device__ __forceinline__ void conv2p_full(
    const u32 (*c1s)[14][20], u16* dst,
    const u32* __restrict__ w2g, const float bv, const int co, const int y)
{
    float acc[28];
    #pragma unroll
    for (int x = 0; x < 28; ++x) acc[x] = bv;
    const int a0 = (y + 1) & 1;
    for (int aa = 0; aa < 2; ++aa) {
        const int a = a0 + 2 * aa;
        const int iy = (y + 1 - a) >> 1;
        if ((unsigned)iy < 14u) {
            #pragma unroll 2
            for (int cip = 0; cip < 8; ++cip) {
                u32 rr[14];
                *(uint4*)&rr[0]  = *(const uint4*)&c1s[cip][iy][0];
                *(uint4*)&rr[4]  = *(const uint4*)&c1s[cip][iy][4];
                *(uint4*)&rr[8]  = *(const uint4*)&c1s[cip][iy][8];
                *(uint2*)&rr[12] = *(const uint2*)&c1s[cip][iy][12];
                const uint4 wq = *(const uint4*)(w2g + ((cip * 4 + a) * 8 + co) * 4);
                const u32 wv[4] = {wq.x, wq.y, wq.z, wq.w};
                #pragma unroll
                for (int x = 0; x < 28; ++x) {
                    const int c0v = (x + 1) & 1;
                    const int ix0 = (x + 1 - c0v) >> 1;
                    if (ix0 < 14) acc[x] = dot2(rr[ix0],     wv[c0v],     acc[x]);
                    if (ix0 >= 1) acc[x] = dot2(rr[ix0 - 1], wv[c0v + 2], acc[x]);
                }
            }
        }
    }
    #pragma unroll
    for (int x = 0; x < 28; ++x) dst[2 * (1 + x)] = f16b(lrelu(acc[x]));
}

// ---------------------------------------------------------------------------
// Kernel 3: convs, ONE sample per block (gen-sorted via wsi).
// conv1 NOW MFMA: one wave per output parity class (py,px)=(wave>>1,wave&1).
// Per parity: out[16co][49pos] = sum_t A_t[16co][32ci] * B_t[32ci][pos],
//   B_t = h2 shifted by (py-(t>>1), px-(t&1)) — read direct from zero-padded
//   h2s[16cip][9][10] (rows/cols +1 offset), 4 ds_read_b32 per B-frag,
//   cip stride 90 words -> q-groups at banks 0/8/16/24 (conflict-free).
// A-frags: 4 x 16B global loads/lane from apk1 (L1/L2-hot), held in VGPRs.
// D layout [m89]: col(pos)=lane&15, row(co)=(lane>>4)*4+reg.
// conv2/conv3 unchanged (dot2).
// ---------------------------------------------------------------------------
__global__ __launch_bounds__(256, 6) void conv_kernel(
    const int* __restrict__ g_idx, const int* __restrict__ wsi,
    const u16* __restrict__ apk1, const float* __restrict__ cb1,
    const u32* __restrict__ wpk2, const float* __restrict__ cb2,
    const u32* __restrict__ wpk3, const float* __restrict__ cb3,
    const u16* __restrict__ h2g, float* __restrict__ out)
{
    __shared__ __align__(16) char smem[8960 + 13440];
    u32 (*c1s)[14][20] = (u32 (*)[14][20])smem;              // [8cip][14][20] 8960 B
    u32 (*h2s)[9][10]  = (u32 (*)[9][10])(smem + 8960);      // [16cip][9][10] 5760 B
    u32 (*c2s)[28][30] = (u32 (*)[28][30])(smem + 8960);     // [4cip][28][30] aliases h2s
    __shared__ u32 w3s[36];
    __shared__ float sc1[16];

    const int tid = threadIdx.x;
    const int b = wsi[16 + blockIdx.x];
    if (b < 0) return;
    const int g = g_idx[b];
    const u16* a1g = apk1 + g * 8192;
    const u32* w2g = wpk2 + g * 1024;
    const float* cb2g = cb2 + g * 8;
    const float  cb3v = cb3[g];

    // zero h2s borders (rows 0,8 full; cols 0,8,9 of rows 1..7): 41 words/cip
    for (int i = tid; i < 656; i += 256) {
        const int cip = i / 41, rem = i % 41;
        int r, c;
        if (rem < 10)      { r = 0; c = rem; }
        else if (rem < 20) { r = 8; c = rem - 10; }
        else { const int j = rem - 20; r = 1 + j / 3;
               const int jm = j % 3; c = (jm == 0) ? 0 : (jm == 1 ? 8 : 9); }
        h2s[cip][r][c] = 0u;
    }
    // stage h2 interior (x=0..6 only; x=7 in h2g is never written by fc2)
    if (tid < 224) {
        const uint4 qv = ((const uint4*)(h2g + (size_t)b * H2_ELEMS))[tid];
        const int ci = tid / 7, yq = tid % 7;
        u16* dst = (u16*)&h2s[ci >> 1][yq + 1][1] + (ci & 1);
        const u32 w[4] = {qv.x, qv.y, qv.z, qv.w};
        #pragma unroll
        for (int j = 0; j < 3; ++j) {
            dst[4 * j]     = (u16)(w[j] & 0xffffu);
            dst[4 * j + 2] = (u16)(w[j] >> 16);
        }
        dst[12] = (u16)(w[3] & 0xffffu);
    }
    if (tid < 36) w3s[tid] = wpk3[g * 36 + tid];
    if (tid < 16) sc1[tid] = cb1[g * 16 + tid];
    __syncthreads();

    // ---- conv1 via MFMA: wave = parity class ----
    {
        const int wv_ = tid >> 6;
        const int py = wv_ >> 1, px = wv_ & 1;
        const int lane = tid & 63;
        const int n = lane & 15;           // pos-in-tile (B col / D col)
        const int q = lane >> 4;
        // A-frags: apk1[par][t][co=lane&15][ci q*8..q*8+7], 16B each
        const u16* ag = a1g + ((py * 2 + px) * 4) * 512 + n * 32 + q * 8;
        f16x8 af[4];
        #pragma unroll
        for (int t = 0; t < 4; ++t) af[t] = *(const f16x8*)(ag + t * 512);

        int oyv[4], oxv[4];
        #pragma unroll
        for (int tile = 0; tile < 4; ++tile) {
            int p = tile * 16 + n; if (p > 48) p = 48;   // clamp: reads stay in h2s
            oyv[tile] = p / 7; oxv[tile] = p % 7;
        }
        f32x4 acc[4];
        #pragma unroll
        for (int tile = 0; tile < 4; ++tile) acc[tile] = (f32x4){0.f, 0.f, 0.f, 0.f};

        #pragma unroll
        for (int t = 0; t < 4; ++t) {
            const int dy = py - (t >> 1) + 1;   // lds row = oy + dy
            const int dx = px - (t & 1) + 1;    // lds col = ox + dx
            #pragma unroll
            for (int tile = 0; tile < 4; ++tile) {
                const int r = oyv[tile] + dy, c = oxv[tile] + dx;
                uint4 bw;
                bw.x = h2s[q * 4 + 0][r][c];
                bw.y = h2s[q * 4 + 1][r][c];
                bw.z = h2s[q * 4 + 2][r][c];
                bw.w = h2s[q * 4 + 3][r][c];
                acc[tile] = __builtin_amdgcn_mfma_f32_16x16x32_f16(
                    af[t], __builtin_bit_cast(f16x8, bw), acc[tile], 0, 0, 0);
            }
        }
        // writeback: D col = pos (lane&15), D row co = q*4+reg
        #pragma unroll
        for (int tile = 0; tile < 4; ++tile) {
            const int pos = tile * 16 + n;
            if (pos < 49) {
                const int y = 2 * oyv[tile] + py, x = 2 * oxv[tile] + px;
                #pragma unroll
                for (int reg = 0; reg < 4; ++reg) {
                    const int m = q * 4 + reg;
                    u16* d = (u16*)&c1s[m >> 1][y][x] + (m & 1);
                    *d = f16b(lrelu(acc[tile][reg] + sc1[m]));
                }
            }
        }
    }
    __syncthreads();   // h2s dead; c2s may be written

    // conv2: [16,14,14] -> [8,28,28] into padded c2s; also zero pad columns.
    if (tid < 224) {
        const int zc = tid / 56, zr = tid % 56;
        c2s[zc][zr % 28][(zr < 28) ? 0 : 29] = 0u;
        const int co = tid / 28, y = tid % 28;
        const float bv = cb2g[co];
        u16* dst = (u16*)&c2s[co >> 1][y][0] + (co & 1);
        conv2p_full(c1s, dst, w2g, bv, co, y);
    }
    __syncthreads();

    // conv3: [8,28,28] -> [1,28,28], k=3 s=1; padded columns -> vec reads
    if (tid < 196) {
        const int y = tid / 7, qq = tid % 7;
        const int xb = qq * 4;
        float acc[4] = {cb3v, cb3v, cb3v, cb3v};
        #pragma unroll 2
        for (int cip = 0; cip < 4; ++cip) {
            u32 wp[9];
            #pragma unroll
            for (int j = 0; j < 9; ++j) wp[j] = w3s[cip * 9 + j];
            #pragma unroll
            for (int a = 0; a < 3; ++a) {
                const int iy = y + 1 - a;
                if ((unsigned)iy < 28u) {
                    u32 rr[6];
                    *(uint2*)&rr[0] = *(const uint2*)&c2s[cip][iy][xb];
                    *(uint2*)&rr[2] = *(const uint2*)&c2s[cip][iy][xb + 2];
                    *(uint2*)&rr[4] = *(const uint2*)&c2s[cip][iy][xb + 4];
                    #pragma unroll
                    for (int xx = 0; xx < 4; ++xx)
                        #pragma unroll
                        for (int c = 0; c < 3; ++c)
                            acc[xx] = dot2(rr[xx + 2 - c], wp[a * 3 + c], acc[xx]);
                }
            }
        }
        float* op = out + (size_t)b * 784 + y * 28 + xb;
        #pragma unroll
        for (int xx = 0; xx < 4; ++xx) op[xx] = fast_tanh(acc[xx]);
    }
}

extern "C" void kernel_launch(void* const* d_in, const int* in_sizes, int n_in,
                              void* d_out, int out_size, void* d_ws, size_t ws_size,
                              hipStream_t stream) {
    const float* z   = (const float*)d_in[0];
    const int*   gi  = (const int*)d_in[1];
    const float* W1  = (const float*)d_in[2];
    const float* b1  = (const float*)d_in[3];
    const float* W2  = (const float*)d_in[4];
    const float* b2  = (const float*)d_in[5];
    const float* cw1 = (const float*)d_in[6];
    const float* cb1 = (const float*)d_in[7];
    const float* cw2 = (const float*)d_in[8];
    const float* cb2 = (const float*)d_in[9];
    const float* cw3 = (const float*)d_in[10];
    const float* cb3 = (const float*)d_in[11];
    int*      wsi = (int*)d_ws;
    float*    h1g = (float*)((char*)d_ws + WS_H1_OFF);
    u16*      h2g = (u16*)((char*)d_ws + WS_H2_OFF);
    _Float16* w2t = (_Float16*)((char*)d_ws + WS_W2T_OFF);
    u16*      apk1 = (u16*)((char*)d_ws + WS_WPK1_OFF);
    u32*      wpk2 = (u32*)((char*)d_ws + WS_WPK2_OFF);
    u32*      wpk3 = (u32*)((char*)d_ws + WS_WPK3_OFF);

    prep_kernel<<<NB_PREP + NGEN + 1, 256, 0, stream>>>(z, gi, W1, b1, W2, wsi,
                                                        h1g, w2t, cw1, cw2, cw3,
                                                        apk1, wpk2, wpk3);
    fc2_kernel<<<MAXG * NCT, 256, 0, stream>>>(gi, w2t, b2, wsi, h1g, h2g);
    conv_kernel<<<MAXG * GRPS, 256, 0, stream>>>(gi, wsi, apk1, cb1, wpk2, cb2,
                                                 wpk3, cb3, h2g, (float*)d_out);
}

// Round 9
// 147.373 us; speedup vs baseline: 1.1609x; 1.0066x over previous
//
#include <hip/hip_runtime.h>
#include <cstdint>
#include <cstddef>

#define BATCH 2048
#define NZ 128
#define NGEN 8
#define GRPS 32                 // samples per group (same generator)
#define MAXG 72                 // max padded groups
#define NCT 7                   // fc2 col tiles of 256 (6 full + tail 32)
#define H2_ELEMS 1792           // 32*7*8 (x padded 7->8) per sample, f16
#define WS_H1_OFF 16384                                  // h1: 72*8192 fp32
#define WS_H2_OFF (16384 + MAXG * 8192 * 4)              // 2375680
#define WS_W2T_OFF (WS_H2_OFF + BATCH * H2_ELEMS * 2)    // 9715712
#define W2T_GSTRIDE (1568 * 256)                         // fp16 elems per gen
#define NB_W2T (NGEN * 49)                               // 392
#define NB_PREP (NB_W2T + MAXG * 4)                      // 680
// conv weights: apk1 = conv1 MFMA A-pack [g][par4][t4][co16][ci32] f16
//               apk2 = conv2 MFMA A-pack [g][par4][pair2][co16][k32] f16
//               wpk3[g][cip4][9] f16x2
#define WS_WPK1_OFF (WS_W2T_OFF + NGEN * W2T_GSTRIDE * 2)  // 16138240 (16B aligned)
#define WS_APK2_OFF (WS_WPK1_OFF + NGEN * 8192 * 2)
#define WS_WPK3_OFF (WS_APK2_OFF + NGEN * 4096 * 2)
#define PS 304                  // fc2 epilogue LDS row stride (u16); max span+slack 300

typedef unsigned int u32;
typedef unsigned short u16;
typedef unsigned long long u64;
typedef _Float16 f16x8 __attribute__((ext_vector_type(8)));
typedef _Float16 f16x4 __attribute__((ext_vector_type(4)));
typedef _Float16 f16x2 __attribute__((ext_vector_type(2)));
typedef float f32x4 __attribute__((ext_vector_type(4)));

__device__ __forceinline__ float lrelu(float x) { return fmaxf(x, 0.2f * x); }
__device__ __forceinline__ u16 f16b(float f) {
    _Float16 h = (_Float16)f;
    return __builtin_bit_cast(u16, h);
}
__device__ __forceinline__ u32 pk2(float a, float b) {
    f16x2 v; v[0] = (_Float16)a; v[1] = (_Float16)b;
    return __builtin_bit_cast(u32, v);
}
// 2-wide f16 dot with f32 accumulate: v_dot2_f32_f16 (2 MACs/instr, full rate)
__device__ __forceinline__ float dot2(u32 a, u32 b, float c) {
#if __has_builtin(__builtin_amdgcn_fdot2)
    return __builtin_amdgcn_fdot2(__builtin_bit_cast(f16x2, a),
                                  __builtin_bit_cast(f16x2, b), c, false);
#else
    float d;
    asm("v_dot2_f32_f16 %0, %1, %2, %3" : "=v"(d) : "v"(a), "v"(b), "v"(c));
    return d;
#endif
}
__device__ __forceinline__ float fast_tanh(float x) {
    x = fminf(fmaxf(x, -9.f), 9.f);
    const float e = __expf(2.f * x);
    return (e - 1.f) / (e + 1.f);
}
// h2 storage offset for fc2 column n (strictly monotone in n)
__device__ __forceinline__ int h2off(int n) {
    const int ci = n / 49, rm = n % 49;
    return ci * 56 + (rm / 7) * 8 + (rm % 7);
}

// ---------------------------------------------------------------------------
// Kernel 1: prep. Roles by blockIdx:
//   [0, NB_W2T)            : W2 transpose -> W2T f16
//   [NB_W2T, NB_PREP)      : grouped FC1 (locally recomputes binning)
//   [NB_PREP, NB_PREP+NGEN): conv-weight packing (apk1/apk2 MFMA-packs + wpk3)
//   NB_PREP+NGEN           : bin publisher (writes wsi for fc2/conv)
// ---------------------------------------------------------------------------
__global__ __launch_bounds__(256) void prep_kernel(
    const float* __restrict__ z, const int* __restrict__ g_idx,
    const float* __restrict__ W1, const float* __restrict__ b1,
    const float* __restrict__ W2, int* __restrict__ wsi,
    float* __restrict__ h1g, _Float16* __restrict__ W2T,
    const float* __restrict__ cw1, const float* __restrict__ cw2,
    const float* __restrict__ cw3,
    u16* __restrict__ apk1, u16* __restrict__ apk2, u32* __restrict__ wpk3)
{
    __shared__ __align__(16) char pmem[16896];   // roles alias this region

    const int tid = threadIdx.x;
    const int bx = blockIdx.x;

    if (bx < NB_W2T) {
        // ---- W2 transpose role: W2[g][k256][n1568] fp32 -> W2T[g][n][k] fp16
        _Float16 (*t)[264] = (_Float16 (*)[264])pmem;   // 16.5 KB
        const int g = bx / 49;
        const int n0 = (bx % 49) * 32;
        const float* src = W2 + (size_t)g * 256 * 1568;
        const int nl = tid & 31, kh = tid >> 5;
        #pragma unroll 8
        for (int p = 0; p < 32; ++p) {
            const int k = p * 8 + kh;
            t[nl][k] = (_Float16)src[(size_t)k * 1568 + n0 + nl];
        }
        __syncthreads();
        _Float16* dst = W2T + (size_t)g * W2T_GSTRIDE + (size_t)n0 * 256;
        #pragma unroll
        for (int ii = 0; ii < 4; ++ii) {
            const int i = tid + 256 * ii;           // 1024 chunks of 16B
            const int n = i >> 5, kc = i & 31;
            *(uint4*)(dst + (size_t)n * 256 + kc * 8) = *(const uint4*)&t[n][kc * 8];
        }
        return;
    }

    if (bx >= NB_PREP && bx < NB_PREP + NGEN) {
        // ---- conv-weight packing role ----
        const int g = bx - NB_PREP;
        // conv1 MFMA A-pack: apk1[par(py*2+px)][t][co][ci] f16,
        //   a = 1-py+2*(t>>1), c = 1-px+2*(t&1).
        const float* c1p = cw1 + g * 8192;             // [32ci][16co][4][4]
        u16* o1 = apk1 + g * 8192;
        for (int i = tid; i < 8192; i += 256) {
            const int ci = i & 31, co = (i >> 5) & 15, t = (i >> 9) & 3;
            const int px = (i >> 11) & 1, py = (i >> 12) & 1;
            const int a = 1 - py + 2 * (t >> 1);
            const int c = 1 - px + 2 * (t & 1);
            o1[i] = f16b(c1p[ci * 256 + co * 16 + a * 4 + c]);
        }
        // conv2 MFMA A-pack: apk2[par][pair][co16][k32], k = t2*16 + ci,
        //   tap t = 2*pair + t2: a = 1-py+2*pair, ccol = 1-px+2*t2.
        //   co rows 8..15 zeroed (conv2 has 8 output channels).
        const float* c2p = cw2 + g * 2048;             // [16ci][8co][4][4]
        u16* o2 = apk2 + g * 4096;
        for (int i = tid; i < 4096; i += 256) {
            const int k = i & 31, co = (i >> 5) & 15;
            const int pair = (i >> 9) & 1, par = (i >> 10) & 3;
            const int py = par >> 1, px = par & 1;
            const int t2 = k >> 4, ci = k & 15;
            const int a = 1 - py + 2 * pair;
            const int ccol = 1 - px + 2 * t2;
            o2[i] = (co < 8) ? f16b(c2p[ci * 128 + co * 16 + a * 4 + ccol]) : (u16)0;
        }
        if (tid < 36) {                                // [8ci][1co][3][3]
            const int cip = tid / 9, r = tid % 9;
            const float* s = cw3 + g * 72 + cip * 18 + r;
            wpk3[g * 36 + tid] = pk2(s[0], s[9]);
        }
        return;
    }

    // ---- local binning (shared by fc1 role and bin-publisher role) ----
    u16* rank       = (u16*)pmem;                       // [2048] 4096 B
    int (*wcnt)[NGEN]  = (int (*)[NGEN])(pmem + 4096);  // [4][8]
    int (*wboff)[NGEN] = (int (*)[NGEN])(pmem + 4224);  // [4][8]
    int* pbase      = (int*)(pmem + 4352);              // [9]
    const int w = tid >> 6, lane = tid & 63;
    if (tid < 4 * NGEN) wcnt[tid >> 3][tid & 7] = 0;
    __syncthreads();
    const u64 lt = ((u64)1 << lane) - 1;
    #pragma unroll
    for (int r = 0; r < 8; ++r) {
        const int b = r * 256 + tid;
        const int gg = g_idx[b];
        u64 m[NGEN];
        #pragma unroll
        for (int k = 0; k < NGEN; ++k) m[k] = __ballot(gg == k);
        rank[b] = (u16)((int)__popcll(m[gg] & lt) + wcnt[w][gg]);
        if (lane < NGEN) wcnt[w][lane] += (int)__popcll(m[lane]);
    }
    __syncthreads();
    if (tid == 0) {
        int acc = 0;
        for (int g = 0; g < NGEN; ++g) {
            pbase[g] = acc;
            const int tot = wcnt[0][g] + wcnt[1][g] + wcnt[2][g] + wcnt[3][g];
            acc += ((tot + GRPS - 1) / GRPS) * GRPS;
        }
        pbase[NGEN] = acc;
    }
    __syncthreads();
    if (tid < 32) {
        const int ww = tid >> 3, g = tid & 7;
        int off = pbase[g];
        for (int w2 = 0; w2 < ww; ++w2) off += wcnt[w2][g];
        wboff[ww][g] = off;
    }
    __syncthreads();

    if (bx >= NB_PREP + NGEN) {
        // ---- bin-publisher role: write wsi for fc2/conv ----
        if (tid == 0) wsi[0] = pbase[NGEN];
        for (int i = tid; i < MAXG * GRPS; i += 256) wsi[16 + i] = -1;
        __syncthreads();
        #pragma unroll
        for (int r = 0; r < 8; ++r) {
            const int b = r * 256 + tid;
            const int gg = g_idx[b];
            wsi[16 + wboff[w][gg] + (int)rank[b]] = b;
        }
        return;
    }

    // ---- FC1 role (grouped): (group, 8-sample slice) ----
    const int bx2 = bx - NB_W2T;
    const int grp = bx2 >> 2;
    const int s0 = (bx2 & 3) * 8;
    if (grp * GRPS >= pbase[NGEN]) return;

    int gsel = 0;
    #pragma unroll
    for (int g = 1; g < NGEN; ++g) if (grp * GRPS >= pbase[g]) gsel = g;

    int* sb = (int*)(pmem + 4400);                     // [8]
    float (*zst)[12] = (float (*)[12])(pmem + 4608);   // [128][12] 6144 B
    if (tid < 8) sb[tid] = -1;
    __syncthreads();
    const int base = grp * GRPS + s0;
    #pragma unroll
    for (int r = 0; r < 8; ++r) {
        const int b = r * 256 + tid;
        const int gg = g_idx[b];
        const int rel = wboff[w][gg] + (int)rank[b] - base;
        if ((unsigned)rel < 8u) sb[rel] = b;
    }
    __syncthreads();

    const float* W1g = W1 + gsel * (NZ * 256);
    const float* b1g = b1 + gsel * 256;

    {   // stage z: 8 samples x 128 = 256 float4, one per thread
        const int s = tid >> 5, f = tid & 31;
        float4 v = make_float4(0.f, 0.f, 0.f, 0.f);
        if (sb[s] >= 0) v = *(const float4*)(z + (size_t)sb[s] * NZ + 4 * f);
        zst[4 * f + 0][s] = v.x; zst[4 * f + 1][s] = v.y;
        zst[4 * f + 2][s] = v.z; zst[4 * f + 3][s] = v.w;
    }
    __syncthreads();

    const int c = tid;
    float acc[8];
    #pragma unroll
    for (int s = 0; s < 8; ++s) acc[s] = 0.f;
    const float* wp = W1g + c;
    #pragma unroll 4
    for (int k = 0; k < NZ; ++k) {
        const float wv = wp[k * 256];
        float av[8];
        *(float4*)&av[0] = *(const float4*)&zst[k][0];
        *(float4*)&av[4] = *(const float4*)&zst[k][4];
        #pragma unroll
        for (int s = 0; s < 8; ++s) acc[s] += av[s] * wv;
    }
    const float bv = b1g[c];
    float* hp = h1g + (size_t)grp * 8192 + (size_t)s0 * 256 + c;
    #pragma unroll
    for (int s = 0; s < 8; ++s) hp[s * 256] = lrelu(acc[s] + bv);
}

// ---------------------------------------------------------------------------
// Kernel 2: FC2 via fp16 MFMA 16x16x32 — staged A + wide 256-col tiles.
// ---------------------------------------------------------------------------
__global__ __launch_bounds__(256) void fc2_kernel(
    const int* __restrict__ g_idx,
    const _Float16* __restrict__ W2T, const float* __restrict__ b2,
    const int* __restrict__ wsi, const float* __restrict__ h1g,
    u16* __restrict__ h2g)
{
    __shared__ __align__(16) char afsm[GRPS * PS * 2];   // 19456B; afrag uses 16384
    _Float16* afrag = (_Float16*)afsm;
    __shared__ int sb[GRPS];
    __shared__ int sG;

    const int tid = threadIdx.x;
    const int grp = blockIdx.x / NCT;
    const int tile = blockIdx.x % NCT;
    if (grp * GRPS >= wsi[0]) return;   // whole block uniform: before barriers

    if (tid == 0) sG = g_idx[wsi[16 + grp * GRPS]];
    if (tid < GRPS) sb[tid] = wsi[16 + grp * GRPS + tid];
    __syncthreads();
    const _Float16* W2Tg = W2T + (size_t)sG * W2T_GSTRIDE;
    const float* b2g = b2 + sG * 1568;

    // ---- stage A fragments (single f16), conflict-free stores ----
    {
        const float4* h1p4 = (const float4*)(h1g + (size_t)grp * 8192);
        #pragma unroll
        for (int i = 0; i < 8; ++i) {
            const int u = tid + 256 * i;
            const int j4 = u & 1;                  // j base = 4*j4
            const int ln = (u >> 1) & 63;
            const int kq = (u >> 7) & 7;
            const int mt = (u >> 10) & 1;
            const int s = mt * 16 + (ln & 15);
            const float4 v = h1p4[s * 64 + kq * 8 + ((ln >> 4) << 1) + j4];
            f16x4 hi;
            hi[0] = (_Float16)v.x; hi[1] = (_Float16)v.y;
            hi[2] = (_Float16)v.z; hi[3] = (_Float16)v.w;
            const int bh = ((mt * 8 + kq) * 64 + ln) * 8 + 4 * j4;
            *(f16x4*)&afrag[bh] = hi;   // addr = base + 8*u bytes: conflict-free
        }
    }
    __syncthreads();

    const int wave = tid >> 6;
    const int lane = tid & 63;
    const int q = lane >> 4;
    const int nl = lane & 15;
    // wave covers 64 cols: nb(nt) = tile*256 + wave*64 + nt*16, nt=0..3
    const int nbw = tile * 256 + wave * 64;

    f32x4 accA[4], accB[4];
    #pragma unroll
    for (int nt = 0; nt < 4; ++nt) {
        accA[nt] = (f32x4){0.f, 0.f, 0.f, 0.f};
        accB[nt] = accA[nt];
    }
    #pragma unroll
    for (int nt = 0; nt < 4; ++nt) {
        const int nb = nbw + nt * 16;
        if (nb < 1568) {
            const _Float16* bp = W2Tg + (size_t)(nb + nl) * 256 + q * 8;
            #pragma unroll
            for (int kq = 0; kq < 8; ++kq) {
                const f16x8 b = *(const f16x8*)(bp + kq * 32);
                const f16x8 a0 = *(const f16x8*)&afrag[((0 * 8 + kq) * 64 + lane) * 8];
                const f16x8 a1 = *(const f16x8*)&afrag[((1 * 8 + kq) * 64 + lane) * 8];
                accA[nt] = __builtin_amdgcn_mfma_f32_16x16x32_f16(a0, b, accA[nt], 0, 0, 0);
                accB[nt] = __builtin_amdgcn_mfma_f32_16x16x32_f16(a1, b, accB[nt], 0, 0, 0);
            }
        }
    }
    __syncthreads();               // all afrag reads done; reuse as pst

    u16* pst = (u16*)afsm;         // [GRPS][PS] indexed manually
    const int nstart = tile * 256;
    const int nend = (nstart + 256 < 1568) ? nstart + 256 : 1568;
    const int offLo = h2off(nstart), offHi = h2off(nend - 1);
    const int lo8 = offLo & ~7;

    #pragma unroll
    for (int nt = 0; nt < 4; ++nt) {
        const int nb = nbw + nt * 16;
        if (nb < 1568) {
            const int n = nb + nl;
            const float bias = b2g[n];
            u16* pp = pst + (h2off(n) - lo8);
            #pragma unroll
            for (int reg = 0; reg < 4; ++reg) {
                pp[(q * 4 + reg) * PS]      = f16b(lrelu(accA[nt][reg] + bias));
                pp[(16 + q * 4 + reg) * PS] = f16b(lrelu(accB[nt][reg] + bias));
            }
        }
    }
    __syncthreads();

    // ---- coalesced copy-out: 8 threads per sample ----
    {
        const int s = tid >> 3, p = tid & 7;
        const int bb = sb[s];
        if (bb >= 0) {
            u16* row = h2g + (size_t)bb * H2_ELEMS;
            const u16* ps = pst + s * PS - lo8;        // index by off directly
            const int c0 = (offLo + 7) & ~7;           // first aligned chunk
            const int c1 = (offHi + 1) & ~7;           // end of aligned chunks
            for (int o = offLo + p; o < c0 && o <= offHi; o += 8) row[o] = ps[o];
            const int t0 = (c1 > offLo) ? c1 : offLo;
            for (int o = t0 + p; o <= offHi; o += 8) row[o] = ps[o];
            for (int c = c0 + p * 8; c + 8 <= c1; c += 64)
                *(uint4*)(row + c) = *(const uint4*)(ps + c);
        }
    }
}

// ---------------------------------------------------------------------------
// Kernel 3: convs, ONE sample per block (gen-sorted via wsi).
// conv1 AND conv2 via parity MFMA (one wave per output parity class):
//   conv1: out[16co][49pos]  = sum_{t=0..3} A1_t[16co][32ci] * B1_t[32ci][pos]
//   conv2: out[8co][196pos]  = sum_{pair=0,1} A2_p[16co][32k] * B2_p[32k][pos]
//          (k = t2*16+ci packs a tap-PAIR into one K=32 contraction;
//           q-group: t2 = q>>1, cip base = (q&1)*4)
// B read direct from zero-padded LDS; D layout [m89]: col=lane&15, row=q*4+reg.
// LDS: c1w[16r][8cip][17] 8704B (cip stride 17 words: 4 cip reads hit
// distinct banks) | h2s[16cip][9][10] 5760B aliased by c2s[4cip][28][30]
// 13440B after conv1 -> 22144B total.
// conv3 unchanged (dot2).
// ---------------------------------------------------------------------------
__global__ __launch_bounds__(256, 6) void conv_kernel(
    const int* __restrict__ g_idx, const int* __restrict__ wsi,
    const u16* __restrict__ apk1, const float* __restrict__ cb1,
    const u16* __restrict__ apk2, const float* __restrict__ cb2,
    const u32* __restrict__ wpk3, const float* __restrict__ cb3,
    const u16* __restrict__ h2g, float* __restrict__ out)
{
    __shared__ __align__(16) char smem[8704 + 13440];
    u32 (*c1w)[8][17]  = (u32 (*)[8][17])smem;               // [16r][8cip][17] 8704 B
    u32 (*h2s)[9][10]  = (u32 (*)[9][10])(smem + 8704);      // [16cip][9][10] 5760 B
    u32 (*c2s)[28][30] = (u32 (*)[28][30])(smem + 8704);     // [4cip][28][30] aliases h2s
    __shared__ u32 w3s[36];
    __shared__ float sc1[16];
    __shared__ float sc2[8];

    const int tid = threadIdx.x;
    const int b = wsi[16 + blockIdx.x];
    if (b < 0) return;
    const int g = g_idx[b];
    const u16* a1g = apk1 + g * 8192;
    const u16* a2g = apk2 + g * 4096;
    const float  cb3v = cb3[g];

    // zero h2s borders (rows 0,8 full; cols 0,8,9 of rows 1..7): 41 words/cip
    for (int i = tid; i < 656; i += 256) {
        const int cip = i / 41, rem = i % 41;
        int r, c;
        if (rem < 10)      { r = 0; c = rem; }
        else if (rem < 20) { r = 8; c = rem - 10; }
        else { const int j = rem - 20; r = 1 + j / 3;
               const int jm = j % 3; c = (jm == 0) ? 0 : (jm == 1 ? 8 : 9); }
        h2s[cip][r][c] = 0u;
    }
    // zero c1w borders (rows 0,15 full; cols 0,15 of rows 1..14): 496 words
    for (int i = tid; i < 496; i += 256) {
        int r, cip, c;
        if (i < 272) { r = (i < 136) ? 0 : 15; const int rem = i % 136;
                       cip = rem / 17; c = rem % 17; }
        else { const int j = i - 272; r = 1 + (j >> 4); const int k2 = j & 15;
               cip = k2 >> 1; c = (k2 & 1) ? 15 : 0; }
        c1w[r][cip][c] = 0u;
    }
    // stage h2 interior (x=0..6 only; x=7 in h2g is never written by fc2)
    if (tid < 224) {
        const uint4 qv = ((const uint4*)(h2g + (size_t)b * H2_ELEMS))[tid];
        const int ci = tid / 7, yq = tid % 7;
        u16* dst = (u16*)&h2s[ci >> 1][yq + 1][1] + (ci & 1);
        const u32 w[4] = {qv.x, qv.y, qv.z, qv.w};
        #pragma unroll
        for (int j = 0; j < 3; ++j) {
            dst[4 * j]     = (u16)(w[j] & 0xffffu);
            dst[4 * j + 2] = (u16)(w[j] >> 16);
        }
        dst[12] = (u16)(w[3] & 0xffffu);
    }
    if (tid < 36) w3s[tid] = wpk3[g * 36 + tid];
    if (tid < 16) sc1[tid] = cb1[g * 16 + tid];
    if (tid < 8)  sc2[tid] = cb2[g * 8 + tid];
    __syncthreads();

    const int wv_ = tid >> 6;
    const int py = wv_ >> 1, px = wv_ & 1;
    const int lane = tid & 63;
    const int n = lane & 15;           // B/D column within 16-tile
    const int q = lane >> 4;

    // ---- conv1 via MFMA: wave = parity class ----
    {
        const u16* ag = a1g + ((py * 2 + px) * 4) * 512 + n * 32 + q * 8;
        f16x8 af[4];
        #pragma unroll
        for (int t = 0; t < 4; ++t) af[t] = *(const f16x8*)(ag + t * 512);

        int oyv[4], oxv[4];
        #pragma unroll
        for (int tile = 0; tile < 4; ++tile) {
            int p = tile * 16 + n; if (p > 48) p = 48;   // clamp: reads stay in h2s
            oyv[tile] = p / 7; oxv[tile] = p % 7;
        }
        f32x4 acc[4];
        #pragma unroll
        for (int tile = 0; tile < 4; ++tile) acc[tile] = (f32x4){0.f, 0.f, 0.f, 0.f};

        #pragma unroll
        for (int t = 0; t < 4; ++t) {
            const int dy = py - (t >> 1) + 1;   // lds row = oy + dy
            const int dx = px - (t & 1) + 1;    // lds col = ox + dx
            #pragma unroll
            for (int tile = 0; tile < 4; ++tile) {
                const int r = oyv[tile] + dy, c = oxv[tile] + dx;
                uint4 bw;
                bw.x = h2s[q * 4 + 0][r][c];
                bw.y = h2s[q * 4 + 1][r][c];
                bw.z = h2s[q * 4 + 2][r][c];
                bw.w = h2s[q * 4 + 3][r][c];
                acc[tile] = __builtin_amdgcn_mfma_f32_16x16x32_f16(
                    af[t], __builtin_bit_cast(f16x8, bw), acc[tile], 0, 0, 0);
            }
        }
        // writeback into padded c1w: row y+1, col x+1
        #pragma unroll
        for (int tile = 0; tile < 4; ++tile) {
            const int pos = tile * 16 + n;
            if (pos < 49) {
                const int y = 2 * oyv[tile] + py, x = 2 * oxv[tile] + px;
                #pragma unroll
                for (int reg = 0; reg < 4; ++reg) {
                    const int m = q * 4 + reg;
                    u16* d = (u16*)&c1w[y + 1][m >> 1][x + 1] + (m & 1);
                    *d = f16b(lrelu(acc[tile][reg] + sc1[m]));
                }
            }
        }
    }
    __syncthreads();   // c1w complete; h2s dead -> c2s may be written

    // ---- conv2 via MFMA: wave = parity class, tap-pairs as K=32 ----
    {
        // zero c2s pad columns (0 and 29); disjoint from data cols 1..28
        if (tid < 224) {
            const int zc = tid / 56, zr = tid % 56;
            c2s[zc][zr % 28][(zr < 28) ? 0 : 29] = 0u;
        }
        const u16* ag2 = a2g + (py * 2 + px) * 1024 + n * 32 + q * 8;
        const f16x8 af0 = *(const f16x8*)(ag2);
        const f16x8 af1 = *(const f16x8*)(ag2 + 512);
        const int t2 = q >> 1;             // tap column within pair
        const int cipb = (q & 1) * 4;

        #pragma unroll
        for (int tile = 0; tile < 13; ++tile) {
            const int pos = tile * 16 + n;
            const int pv = (pos < 196) ? pos : 195;   // clamp: reads in-bounds
            const int oy = pv / 14, ox = pv % 14;
            const int c = ox + px - t2 + 1;
            f32x4 acc = {0.f, 0.f, 0.f, 0.f};
            {   // pair 0: taps {0,1}, row shift = py - 0 + 1
                const int r = oy + py + 1;
                uint4 bw;
                bw.x = c1w[r][cipb + 0][c];
                bw.y = c1w[r][cipb + 1][c];
                bw.z = c1w[r][cipb + 2][c];
                bw.w = c1w[r][cipb + 3][c];
                acc = __builtin_amdgcn_mfma_f32_16x16x32_f16(
                    af0, __builtin_bit_cast(f16x8, bw), acc, 0, 0, 0);
            }
            {   // pair 1: taps {2,3}, row shift = py - 1 + 1
                const int r = oy + py;
                uint4 bw;
                bw.x = c1w[r][cipb + 0][c];
                bw.y = c1w[r][cipb + 1][c];
                bw.z = c1w[r][cipb + 2][c];
                bw.w = c1w[r][cipb + 3][c];
                acc = __builtin_amdgcn_mfma_f32_16x16x32_f16(
                    af1, __builtin_bit_cast(f16x8, bw), acc, 0, 0, 0);
            }
            if (pos < 196 && q < 2) {      // D rows 0..7 = co; rows 8..15 unused
                const int y = 2 * oy + py, x = 2 * ox + px;
                #pragma unroll
                for (int reg = 0; reg < 4; ++reg) {
                    const int co = q * 4 + reg;
                    u16* d = (u16*)&c2s[co >> 1][y][1 + x] + (co & 1);
                    *d = f16b(lrelu(acc[reg] + sc2[co]));
                }
            }
        }
    }
    __syncthreads();

    // conv3: [8,28,28] -> [1,28,28], k=3 s=1; padded columns -> vec reads
    if (tid < 196) {
        const int y = tid / 7, qq = tid % 7;
        const int xb = qq * 4;
        float acc[4] = {cb3v, cb3v, cb3v, cb3v};
        #pragma unroll 2
        for (int cip = 0; cip < 4; ++cip) {
            u32 wp[9];
            #pragma unroll
            for (int j = 0; j < 9; ++j) wp[j] = w3s[cip * 9 + j];
            #pragma unroll
            for (int a = 0; a < 3; ++a) {
                const int iy = y + 1 - a;
                if ((unsigned)iy < 28u) {
                    u32 rr[6];
                    *(uint2*)&rr[0] = *(const uint2*)&c2s[cip][iy][xb];
                    *(uint2*)&rr[2] = *(const uint2*)&c2s[cip][iy][xb + 2];
                    *(uint2*)&rr[4] = *(const uint2*)&c2s[cip][iy][xb + 4];
                    #pragma unroll
                    for (int xx = 0; xx < 4; ++xx)
                        #pragma unroll
                        for (int c = 0; c < 3; ++c)
                            acc[xx] = dot2(rr[xx + 2 - c], wp[a * 3 + c], acc[xx]);
                }
            }
        }
        float* op = out + (size_t)b * 784 + y * 28 + xb;
        #pragma unroll
        for (int xx = 0; xx < 4; ++xx) op[xx] = fast_tanh(acc[xx]);
    }
}

extern "C" void kernel_launch(void* const* d_in, const int* in_sizes, int n_in,
                              void* d_out, int out_size, void* d_ws, size_t ws_size,
                              hipStream_t stream) {
    const float* z   = (const float*)d_in[0];
    const int*   gi  = (const int*)d_in[1];
    const float* W1  = (const float*)d_in[2];
    const float* b1  = (const float*)d_in[3];
    const float* W2  = (const float*)d_in[4];
    const float* b2  = (const float*)d_in[5];
    const float* cw1 = (const float*)d_in[6];
    const float* cb1 = (const float*)d_in[7];
    const float* cw2 = (const float*)d_in[8];
    const float* cb2 = (const float*)d_in[9];
    const float* cw3 = (const float*)d_in[10];
    const float* cb3 = (const float*)d_in[11];
    int*      wsi = (int*)d_ws;
    float*    h1g = (float*)((char*)d_ws + WS_H1_OFF);
    u16*      h2g = (u16*)((char*)d_ws + WS_H2_OFF);
    _Float16* w2t = (_Float16*)((char*)d_ws + WS_W2T_OFF);
    u16*      apk1 = (u16*)((char*)d_ws + WS_WPK1_OFF);
    u16*      apk2 = (u16*)((char*)d_ws + WS_APK2_OFF);
    u32*      wpk3 = (u32*)((char*)d_ws + WS_WPK3_OFF);

    prep_kernel<<<NB_PREP + NGEN + 1, 256, 0, stream>>>(z, gi, W1, b1, W2, wsi,
                                                        h1g, w2t, cw1, cw2, cw3,
                                                        apk1, apk2, wpk3);
    fc2_kernel<<<MAXG * NCT, 256, 0, stream>>>(gi, w2t, b2, wsi, h1g, h2g);
    conv_kernel<<<MAXG * GRPS, 256, 0, stream>>>(gi, wsi, apk1, cb1, apk2, cb2,
                                                 wpk3, cb3, h2g, (float*)d_out);
}

// Round 10
// 144.383 us; speedup vs baseline: 1.1850x; 1.0207x over previous
//
#include <hip/hip_runtime.h>
#include <cstdint>
#include <cstddef>

#define BATCH 2048
#define NZ 128
#define NGEN 8
#define GRPS 32                 // samples per group (same generator)
#define MAXG 72                 // max padded groups
#define NCT 7                   // fc2 col tiles of 256 (6 full + tail 32)
#define H2_ELEMS 1792           // 32*7*8 (x padded 7->8) per sample, f16
#define WS_H1_OFF 16384                                  // h1f: 72*8192 f16 (afrag order)
#define WS_H2_OFF (16384 + MAXG * 8192 * 4)              // 2375680
#define WS_W2T_OFF (WS_H2_OFF + BATCH * H2_ELEMS * 2)    // 9715712
#define W2T_GSTRIDE (1568 * 256)                         // fp16 elems per gen
#define NB_W2T (NGEN * 49)                               // 392
#define NB_PREP (NB_W2T + MAXG * 4)                      // 680
// conv weights: apk1 = conv1 MFMA A-pack [g][par4][t4][co16][ci32] f16
//               apk2 = conv2 MFMA A-pack [g][par4][pair2][co16][k32] f16
//               wpk3[g][cip4][9] f16x2
#define WS_WPK1_OFF (WS_W2T_OFF + NGEN * W2T_GSTRIDE * 2)  // 16138240 (16B aligned)
#define WS_APK2_OFF (WS_WPK1_OFF + NGEN * 8192 * 2)
#define WS_WPK3_OFF (WS_APK2_OFF + NGEN * 4096 * 2)
#define PS 304                  // fc2 epilogue LDS row stride (u16); max span+slack 300

typedef unsigned int u32;
typedef unsigned short u16;
typedef unsigned long long u64;
typedef _Float16 f16x8 __attribute__((ext_vector_type(8)));
typedef _Float16 f16x4 __attribute__((ext_vector_type(4)));
typedef _Float16 f16x2 __attribute__((ext_vector_type(2)));
typedef float f32x4 __attribute__((ext_vector_type(4)));

__device__ __forceinline__ float lrelu(float x) { return fmaxf(x, 0.2f * x); }
__device__ __forceinline__ u16 f16b(float f) {
    _Float16 h = (_Float16)f;
    return __builtin_bit_cast(u16, h);
}
__device__ __forceinline__ u32 pk2(float a, float b) {
    f16x2 v; v[0] = (_Float16)a; v[1] = (_Float16)b;
    return __builtin_bit_cast(u32, v);
}
// 2-wide f16 dot with f32 accumulate: v_dot2_f32_f16 (2 MACs/instr, full rate)
__device__ __forceinline__ float dot2(u32 a, u32 b, float c) {
#if __has_builtin(__builtin_amdgcn_fdot2)
    return __builtin_amdgcn_fdot2(__builtin_bit_cast(f16x2, a),
                                  __builtin_bit_cast(f16x2, b), c, false);
#else
    float d;
    asm("v_dot2_f32_f16 %0, %1, %2, %3" : "=v"(d) : "v"(a), "v"(b), "v"(c));
    return d;
#endif
}
__device__ __forceinline__ float fast_tanh(float x) {
    x = fminf(fmaxf(x, -9.f), 9.f);
    const float e = __expf(2.f * x);
    return (e - 1.f) / (e + 1.f);
}
// h2 storage offset for fc2 column n (strictly monotone in n)
__device__ __forceinline__ int h2off(int n) {
    const int ci = n / 49, rm = n % 49;
    return ci * 56 + (rm / 7) * 8 + (rm % 7);
}

// ---------------------------------------------------------------------------
// Kernel 1: prep. Roles by blockIdx:
//   [0, NB_W2T)            : W2 transpose -> W2T f16
//   [NB_W2T, NB_PREP)      : grouped FC1 (locally recomputes binning).
//                            h1 is emitted as f16 DIRECTLY IN afrag element
//                            order -> fc2 staging is a linear 16KB copy.
//   [NB_PREP, NB_PREP+NGEN): conv-weight packing (apk1/apk2 MFMA-packs + wpk3)
//   NB_PREP+NGEN           : bin publisher (writes wsi for fc2/conv)
// ---------------------------------------------------------------------------
__global__ __launch_bounds__(256) void prep_kernel(
    const float* __restrict__ z, const int* __restrict__ g_idx,
    const float* __restrict__ W1, const float* __restrict__ b1,
    const float* __restrict__ W2, int* __restrict__ wsi,
    u16* __restrict__ h1f, _Float16* __restrict__ W2T,
    const float* __restrict__ cw1, const float* __restrict__ cw2,
    const float* __restrict__ cw3,
    u16* __restrict__ apk1, u16* __restrict__ apk2, u32* __restrict__ wpk3)
{
    __shared__ __align__(16) char pmem[16896];   // roles alias this region

    const int tid = threadIdx.x;
    const int bx = blockIdx.x;

    if (bx < NB_W2T) {
        // ---- W2 transpose role: W2[g][k256][n1568] fp32 -> W2T[g][n][k] fp16
        _Float16 (*t)[264] = (_Float16 (*)[264])pmem;   // 16.5 KB
        const int g = bx / 49;
        const int n0 = (bx % 49) * 32;
        const float* src = W2 + (size_t)g * 256 * 1568;
        const int nl = tid & 31, kh = tid >> 5;
        #pragma unroll 8
        for (int p = 0; p < 32; ++p) {
            const int k = p * 8 + kh;
            t[nl][k] = (_Float16)src[(size_t)k * 1568 + n0 + nl];
        }
        __syncthreads();
        _Float16* dst = W2T + (size_t)g * W2T_GSTRIDE + (size_t)n0 * 256;
        #pragma unroll
        for (int ii = 0; ii < 4; ++ii) {
            const int i = tid + 256 * ii;           // 1024 chunks of 16B
            const int n = i >> 5, kc = i & 31;
            *(uint4*)(dst + (size_t)n * 256 + kc * 8) = *(const uint4*)&t[n][kc * 8];
        }
        return;
    }

    if (bx >= NB_PREP && bx < NB_PREP + NGEN) {
        // ---- conv-weight packing role ----
        const int g = bx - NB_PREP;
        // conv1 MFMA A-pack: apk1[par(py*2+px)][t][co][ci] f16,
        //   a = 1-py+2*(t>>1), c = 1-px+2*(t&1).
        const float* c1p = cw1 + g * 8192;             // [32ci][16co][4][4]
        u16* o1 = apk1 + g * 8192;
        for (int i = tid; i < 8192; i += 256) {
            const int ci = i & 31, co = (i >> 5) & 15, t = (i >> 9) & 3;
            const int px = (i >> 11) & 1, py = (i >> 12) & 1;
            const int a = 1 - py + 2 * (t >> 1);
            const int c = 1 - px + 2 * (t & 1);
            o1[i] = f16b(c1p[ci * 256 + co * 16 + a * 4 + c]);
        }
        // conv2 MFMA A-pack: apk2[par][pair][co16][k32], k = t2*16 + ci,
        //   tap t = 2*pair + t2: a = 1-py+2*pair, ccol = 1-px+2*t2.
        //   co rows 8..15 zeroed (conv2 has 8 output channels).
        const float* c2p = cw2 + g * 2048;             // [16ci][8co][4][4]
        u16* o2 = apk2 + g * 4096;
        for (int i = tid; i < 4096; i += 256) {
            const int k = i & 31, co = (i >> 5) & 15;
            const int pair = (i >> 9) & 1, par = (i >> 10) & 3;
            const int py = par >> 1, px = par & 1;
            const int t2 = k >> 4, ci = k & 15;
            const int a = 1 - py + 2 * pair;
            const int ccol = 1 - px + 2 * t2;
            o2[i] = (co < 8) ? f16b(c2p[ci * 128 + co * 16 + a * 4 + ccol]) : (u16)0;
        }
        if (tid < 36) {                                // [8ci][1co][3][3]
            const int cip = tid / 9, r = tid % 9;
            const float* s = cw3 + g * 72 + cip * 18 + r;
            wpk3[g * 36 + tid] = pk2(s[0], s[9]);
        }
        return;
    }

    // ---- local binning (shared by fc1 role and bin-publisher role) ----
    u16* rank       = (u16*)pmem;                       // [2048] 4096 B
    int (*wcnt)[NGEN]  = (int (*)[NGEN])(pmem + 4096);  // [4][8]
    int (*wboff)[NGEN] = (int (*)[NGEN])(pmem + 4224);  // [4][8]
    int* pbase      = (int*)(pmem + 4352);              // [9]
    const int w = tid >> 6, lane = tid & 63;
    if (tid < 4 * NGEN) wcnt[tid >> 3][tid & 7] = 0;
    __syncthreads();
    const u64 lt = ((u64)1 << lane) - 1;
    #pragma unroll
    for (int r = 0; r < 8; ++r) {
        const int b = r * 256 + tid;
        const int gg = g_idx[b];
        u64 m[NGEN];
        #pragma unroll
        for (int k = 0; k < NGEN; ++k) m[k] = __ballot(gg == k);
        rank[b] = (u16)((int)__popcll(m[gg] & lt) + wcnt[w][gg]);
        if (lane < NGEN) wcnt[w][lane] += (int)__popcll(m[lane]);
    }
    __syncthreads();
    if (tid == 0) {
        int acc = 0;
        for (int g = 0; g < NGEN; ++g) {
            pbase[g] = acc;
            const int tot = wcnt[0][g] + wcnt[1][g] + wcnt[2][g] + wcnt[3][g];
            acc += ((tot + GRPS - 1) / GRPS) * GRPS;
        }
        pbase[NGEN] = acc;
    }
    __syncthreads();
    if (tid < 32) {
        const int ww = tid >> 3, g = tid & 7;
        int off = pbase[g];
        for (int w2 = 0; w2 < ww; ++w2) off += wcnt[w2][g];
        wboff[ww][g] = off;
    }
    __syncthreads();

    if (bx >= NB_PREP + NGEN) {
        // ---- bin-publisher role: write wsi for fc2/conv ----
        if (tid == 0) wsi[0] = pbase[NGEN];
        for (int i = tid; i < MAXG * GRPS; i += 256) wsi[16 + i] = -1;
        __syncthreads();
        #pragma unroll
        for (int r = 0; r < 8; ++r) {
            const int b = r * 256 + tid;
            const int gg = g_idx[b];
            wsi[16 + wboff[w][gg] + (int)rank[b]] = b;
        }
        return;
    }

    // ---- FC1 role (grouped): (group, 8-sample slice) ----
    const int bx2 = bx - NB_W2T;
    const int grp = bx2 >> 2;
    const int s0 = (bx2 & 3) * 8;
    if (grp * GRPS >= pbase[NGEN]) return;

    int gsel = 0;
    #pragma unroll
    for (int g = 1; g < NGEN; ++g) if (grp * GRPS >= pbase[g]) gsel = g;

    int* sb = (int*)(pmem + 4400);                     // [8]
    float (*zst)[12] = (float (*)[12])(pmem + 4608);   // [128][12] 6144 B
    if (tid < 8) sb[tid] = -1;
    __syncthreads();
    const int base = grp * GRPS + s0;
    #pragma unroll
    for (int r = 0; r < 8; ++r) {
        const int b = r * 256 + tid;
        const int gg = g_idx[b];
        const int rel = wboff[w][gg] + (int)rank[b] - base;
        if ((unsigned)rel < 8u) sb[rel] = b;
    }
    __syncthreads();

    const float* W1g = W1 + gsel * (NZ * 256);
    const float* b1g = b1 + gsel * 256;

    {   // stage z: 8 samples x 128 = 256 float4, one per thread
        const int s = tid >> 5, f = tid & 31;
        float4 v = make_float4(0.f, 0.f, 0.f, 0.f);
        if (sb[s] >= 0) v = *(const float4*)(z + (size_t)sb[s] * NZ + 4 * f);
        zst[4 * f + 0][s] = v.x; zst[4 * f + 1][s] = v.y;
        zst[4 * f + 2][s] = v.z; zst[4 * f + 3][s] = v.w;
    }
    __syncthreads();

    const int c = tid;
    float acc[8];
    #pragma unroll
    for (int s = 0; s < 8; ++s) acc[s] = 0.f;
    const float* wp = W1g + c;
    #pragma unroll 4
    for (int k = 0; k < NZ; ++k) {
        const float wv = wp[k * 256];
        float av[8];
        *(float4*)&av[0] = *(const float4*)&zst[k][0];
        *(float4*)&av[4] = *(const float4*)&zst[k][4];
        #pragma unroll
        for (int s = 0; s < 8; ++s) acc[s] += av[s] * wv;
    }
    const float bv = b1g[c];
    // write h1 as f16 in afrag element order:
    //   idx = ((mt*8+kq)*64 + ln)*8 + 4*j4 + e,
    //   kq=c>>5, l4=(c>>3)&3, j4=(c>>2)&1, e=c&3, ln=l4*16+(s&15), mt=s>>4.
    {
        u16* hp = h1f + (size_t)grp * 8192;
        const int kq = c >> 5, l4 = (c >> 3) & 3, j4 = (c >> 2) & 1, e = c & 3;
        const int mt = s0 >> 4;
        const int bidx = ((mt * 8 + kq) * 64 + l4 * 16) * 8 + 4 * j4 + e;
        #pragma unroll
        for (int ss = 0; ss < 8; ++ss) {
            const int s = s0 + ss;
            hp[bidx + (s & 15) * 8] = f16b(lrelu(acc[ss] + bv));
        }
    }
}

// ---------------------------------------------------------------------------
// Kernel 2: FC2 via fp16 MFMA 16x16x32 — staged A + wide 256-col tiles.
// h1f is already f16 in afrag order -> staging is a linear 16KB copy
// (4 x uint4 per thread; no converts, no index math, half the bytes).
// ---------------------------------------------------------------------------
__global__ __launch_bounds__(256) void fc2_kernel(
    const int* __restrict__ g_idx,
    const _Float16* __restrict__ W2T, const float* __restrict__ b2,
    const int* __restrict__ wsi, const u16* __restrict__ h1f,
    u16* __restrict__ h2g)
{
    __shared__ __align__(16) char afsm[GRPS * PS * 2];   // 19456B; afrag uses 16384
    _Float16* afrag = (_Float16*)afsm;
    __shared__ int sb[GRPS];
    __shared__ int sG;

    const int tid = threadIdx.x;
    const int grp = blockIdx.x / NCT;
    const int tile = blockIdx.x % NCT;
    if (grp * GRPS >= wsi[0]) return;   // whole block uniform: before barriers

    if (tid == 0) sG = g_idx[wsi[16 + grp * GRPS]];
    if (tid < GRPS) sb[tid] = wsi[16 + grp * GRPS + tid];
    __syncthreads();
    const _Float16* W2Tg = W2T + (size_t)sG * W2T_GSTRIDE;
    const float* b2g = b2 + sG * 1568;

    // ---- stage A fragments: linear copy, conflict-free ----
    {
        const u16* src = h1f + (size_t)grp * 8192;
        u16* af16 = (u16*)afsm;
        #pragma unroll
        for (int i = 0; i < 4; ++i) {
            const int eo = (i * 256 + tid) * 8;
            *(uint4*)(af16 + eo) = *(const uint4*)(src + eo);
        }
    }
    __syncthreads();

    const int wave = tid >> 6;
    const int lane = tid & 63;
    const int q = lane >> 4;
    const int nl = lane & 15;
    // wave covers 64 cols: nb(nt) = tile*256 + wave*64 + nt*16, nt=0..3
    const int nbw = tile * 256 + wave * 64;

    f32x4 accA[4], accB[4];
    #pragma unroll
    for (int nt = 0; nt < 4; ++nt) {
        accA[nt] = (f32x4){0.f, 0.f, 0.f, 0.f};
        accB[nt] = accA[nt];
    }
    #pragma unroll
    for (int nt = 0; nt < 4; ++nt) {
        const int nb = nbw + nt * 16;
        if (nb < 1568) {
            const _Float16* bp = W2Tg + (size_t)(nb + nl) * 256 + q * 8;
            #pragma unroll
            for (int kq = 0; kq < 8; ++kq) {
                const f16x8 b = *(const f16x8*)(bp + kq * 32);
                const f16x8 a0 = *(const f16x8*)&afrag[((0 * 8 + kq) * 64 + lane) * 8];
                const f16x8 a1 = *(const f16x8*)&afrag[((1 * 8 + kq) * 64 + lane) * 8];
                accA[nt] = __builtin_amdgcn_mfma_f32_16x16x32_f16(a0, b, accA[nt], 0, 0, 0);
                accB[nt] = __builtin_amdgcn_mfma_f32_16x16x32_f16(a1, b, accB[nt], 0, 0, 0);
            }
        }
    }
    __syncthreads();               // all afrag reads done; reuse as pst

    u16* pst = (u16*)afsm;         // [GRPS][PS] indexed manually
    const int nstart = tile * 256;
    const int nend = (nstart + 256 < 1568) ? nstart + 256 : 1568;
    const int offLo = h2off(nstart), offHi = h2off(nend - 1);
    const int lo8 = offLo & ~7;

    #pragma unroll
    for (int nt = 0; nt < 4; ++nt) {
        const int nb = nbw + nt * 16;
        if (nb < 1568) {
            const int n = nb + nl;
            const float bias = b2g[n];
            u16* pp = pst + (h2off(n) - lo8);
            #pragma unroll
            for (int reg = 0; reg < 4; ++reg) {
                pp[(q * 4 + reg) * PS]      = f16b(lrelu(accA[nt][reg] + bias));
                pp[(16 + q * 4 + reg) * PS] = f16b(lrelu(accB[nt][reg] + bias));
            }
        }
    }
    __syncthreads();

    // ---- coalesced copy-out: 8 threads per sample ----
    {
        const int s = tid >> 3, p = tid & 7;
        const int bb = sb[s];
        if (bb >= 0) {
            u16* row = h2g + (size_t)bb * H2_ELEMS;
            const u16* ps = pst + s * PS - lo8;        // index by off directly
            const int c0 = (offLo + 7) & ~7;           // first aligned chunk
            const int c1 = (offHi + 1) & ~7;           // end of aligned chunks
            for (int o = offLo + p; o < c0 && o <= offHi; o += 8) row[o] = ps[o];
            const int t0 = (c1 > offLo) ? c1 : offLo;
            for (int o = t0 + p; o <= offHi; o += 8) row[o] = ps[o];
            for (int c = c0 + p * 8; c + 8 <= c1; c += 64)
                *(uint4*)(row + c) = *(const uint4*)(ps + c);
        }
    }
}

// ---------------------------------------------------------------------------
// Kernel 3: convs, ONE sample per block (gen-sorted via wsi).
// conv1 AND conv2 via parity MFMA (one wave per output parity class).
// conv3 dot2. Unchanged from r9 (control).
// ---------------------------------------------------------------------------
__global__ __launch_bounds__(256, 6) void conv_kernel(
    const int* __restrict__ g_idx, const int* __restrict__ wsi,
    const u16* __restrict__ apk1, const float* __restrict__ cb1,
    const u16* __restrict__ apk2, const float* __restrict__ cb2,
    const u32* __restrict__ wpk3, const float* __restrict__ cb3,
    const u16* __restrict__ h2g, float* __restrict__ out)
{
    __shared__ __align__(16) char smem[8704 + 13440];
    u32 (*c1w)[8][17]  = (u32 (*)[8][17])smem;               // [16r][8cip][17] 8704 B
    u32 (*h2s)[9][10]  = (u32 (*)[9][10])(smem + 8704);      // [16cip][9][10] 5760 B
    u32 (*c2s)[28][30] = (u32 (*)[28][30])(smem + 8704);     // [4cip][28][30] aliases h2s
    __shared__ u32 w3s[36];
    __shared__ float sc1[16];
    __shared__ float sc2[8];

    const int tid = threadIdx.x;
    const int b = wsi[16 + blockIdx.x];
    if (b < 0) return;
    const int g = g_idx[b];
    const u16* a1g = apk1 + g * 8192;
    const u16* a2g = apk2 + g * 4096;
    const float  cb3v = cb3[g];

    // zero h2s borders (rows 0,8 full; cols 0,8,9 of rows 1..7): 41 words/cip
    for (int i = tid; i < 656; i += 256) {
        const int cip = i / 41, rem = i % 41;
        int r, c;
        if (rem < 10)      { r = 0; c = rem; }
        else if (rem < 20) { r = 8; c = rem - 10; }
        else { const int j = rem - 20; r = 1 + j / 3;
               const int jm = j % 3; c = (jm == 0) ? 0 : (jm == 1 ? 8 : 9); }
        h2s[cip][r][c] = 0u;
    }
    // zero c1w borders (rows 0,15 full; cols 0,15 of rows 1..14): 496 words
    for (int i = tid; i < 496; i += 256) {
        int r, cip, c;
        if (i < 272) { r = (i < 136) ? 0 : 15; const int rem = i % 136;
                       cip = rem / 17; c = rem % 17; }
        else { const int j = i - 272; r = 1 + (j >> 4); const int k2 = j & 15;
               cip = k2 >> 1; c = (k2 & 1) ? 15 : 0; }
        c1w[r][cip][c] = 0u;
    }
    // stage h2 interior (x=0..6 only; x=7 in h2g is never written by fc2)
    if (tid < 224) {
        const uint4 qv = ((const uint4*)(h2g + (size_t)b * H2_ELEMS))[tid];
        const int ci = tid / 7, yq = tid % 7;
        u16* dst = (u16*)&h2s[ci >> 1][yq + 1][1] + (ci & 1);
        const u32 w[4] = {qv.x, qv.y, qv.z, qv.w};
        #pragma unroll
        for (int j = 0; j < 3; ++j) {
            dst[4 * j]     = (u16)(w[j] & 0xffffu);
            dst[4 * j + 2] = (u16)(w[j] >> 16);
        }
        dst[12] = (u16)(w[3] & 0xffffu);
    }
    if (tid < 36) w3s[tid] = wpk3[g * 36 + tid];
    if (tid < 16) sc1[tid] = cb1[g * 16 + tid];
    if (tid < 8)  sc2[tid] = cb2[g * 8 + tid];
    __syncthreads();

    const int wv_ = tid >> 6;
    const int py = wv_ >> 1, px = wv_ & 1;
    const int lane = tid & 63;
    const int n = lane & 15;           // B/D column within 16-tile
    const int q = lane >> 4;

    // ---- conv1 via MFMA: wave = parity class ----
    {
        const u16* ag = a1g + ((py * 2 + px) * 4) * 512 + n * 32 + q * 8;
        f16x8 af[4];
        #pragma unroll
        for (int t = 0; t < 4; ++t) af[t] = *(const f16x8*)(ag + t * 512);

        int oyv[4], oxv[4];
        #pragma unroll
        for (int tile = 0; tile < 4; ++tile) {
            int p = tile * 16 + n; if (p > 48) p = 48;   // clamp: reads stay in h2s
            oyv[tile] = p / 7; oxv[tile] = p % 7;
        }
        f32x4 acc[4];
        #pragma unroll
        for (int tile = 0; tile < 4; ++tile) acc[tile] = (f32x4){0.f, 0.f, 0.f, 0.f};

        #pragma unroll
        for (int t = 0; t < 4; ++t) {
            const int dy = py - (t >> 1) + 1;   // lds row = oy + dy
            const int dx = px - (t & 1) + 1;    // lds col = ox + dx
            #pragma unroll
            for (int tile = 0; tile < 4; ++tile) {
                const int r = oyv[tile] + dy, c = oxv[tile] + dx;
                uint4 bw;
                bw.x = h2s[q * 4 + 0][r][c];
                bw.y = h2s[q * 4 + 1][r][c];
                bw.z = h2s[q * 4 + 2][r][c];
                bw.w = h2s[q * 4 + 3][r][c];
                acc[tile] = __builtin_amdgcn_mfma_f32_16x16x32_f16(
                    af[t], __builtin_bit_cast(f16x8, bw), acc[tile], 0, 0, 0);
            }
        }
        // writeback into padded c1w: row y+1, col x+1
        #pragma unroll
        for (int tile = 0; tile < 4; ++tile) {
            const int pos = tile * 16 + n;
            if (pos < 49) {
                const int y = 2 * oyv[tile] + py, x = 2 * oxv[tile] + px;
                #pragma unroll
                for (int reg = 0; reg < 4; ++reg) {
                    const int m = q * 4 + reg;
                    u16* d = (u16*)&c1w[y + 1][m >> 1][x + 1] + (m & 1);
                    *d = f16b(lrelu(acc[tile][reg] + sc1[m]));
                }
            }
        }
    }
    __syncthreads();   // c1w complete; h2s dead -> c2s may be written

    // ---- conv2 via MFMA: wave = parity class, tap-pairs as K=32 ----
    {
        // zero c2s pad columns (0 and 29); disjoint from data cols 1..28
        if (tid < 224) {
            const int zc = tid / 56, zr = tid % 56;
            c2s[zc][zr % 28][(zr < 28) ? 0 : 29] = 0u;
        }
        const u16* ag2 = a2g + (py * 2 + px) * 1024 + n * 32 + q * 8;
        const f16x8 af0 = *(const f16x8*)(ag2);
        const f16x8 af1 = *(const f16x8*)(ag2 + 512);
        const int t2 = q >> 1;             // tap column within pair
        const int cipb = (q & 1) * 4;

        #pragma unroll
        for (int tile = 0; tile < 13; ++tile) {
            const int pos = tile * 16 + n;
            const int pv = (pos < 196) ? pos : 195;   // clamp: reads in-bounds
            const int oy = pv / 14, ox = pv % 14;
            const int c = ox + px - t2 + 1;
            f32x4 acc = {0.f, 0.f, 0.f, 0.f};
            {   // pair 0: taps {0,1}, row shift = py - 0 + 1
                const int r = oy + py + 1;
                uint4 bw;
                bw.x = c1w[r][cipb + 0][c];
                bw.y = c1w[r][cipb + 1][c];
                bw.z = c1w[r][cipb + 2][c];
                bw.w = c1w[r][cipb + 3][c];
                acc = __builtin_amdgcn_mfma_f32_16x16x32_f16(
                    af0, __builtin_bit_cast(f16x8, bw), acc, 0, 0, 0);
            }
            {   // pair 1: taps {2,3}, row shift = py - 1 + 1
                const int r = oy + py;
                uint4 bw;
                bw.x = c1w[r][cipb + 0][c];
                bw.y = c1w[r][cipb + 1][c];
                bw.z = c1w[r][cipb + 2][c];
                bw.w = c1w[r][cipb + 3][c];
                acc = __builtin_amdgcn_mfma_f32_16x16x32_f16(
                    af1, __builtin_bit_cast(f16x8, bw), acc, 0, 0, 0);
            }
            if (pos < 196 && q < 2) {      // D rows 0..7 = co; rows 8..15 unused
                const int y = 2 * oy + py, x = 2 * ox + px;
                #pragma unroll
                for (int reg = 0; reg < 4; ++reg) {
                    const int co = q * 4 + reg;
                    u16* d = (u16*)&c2s[co >> 1][y][1 + x] + (co & 1);
                    *d = f16b(lrelu(acc[reg] + sc2[co]));
                }
            }
        }
    }
    __syncthreads();

    // conv3: [8,28,28] -> [1,28,28], k=3 s=1; padded columns -> vec reads
    if (tid < 196) {
        const int y = tid / 7, qq = tid % 7;
        const int xb = qq * 4;
        float acc[4] = {cb3v, cb3v, cb3v, cb3v};
        #pragma unroll 2
        for (int cip = 0; cip < 4; ++cip) {
            u32 wp[9];
            #pragma unroll
            for (int j = 0; j < 9; ++j) wp[j] = w3s[cip * 9 + j];
            #pragma unroll
            for (int a = 0; a < 3; ++a) {
                const int iy = y + 1 - a;
                if ((unsigned)iy < 28u) {
                    u32 rr[6];
                    *(uint2*)&rr[0] = *(const uint2*)&c2s[cip][iy][xb];
                    *(uint2*)&rr[2] = *(const uint2*)&c2s[cip][iy][xb + 2];
                    *(uint2*)&rr[4] = *(const uint2*)&c2s[cip][iy][xb + 4];
                    #pragma unroll
                    for (int xx = 0; xx < 4; ++xx)
                        #pragma unroll
                        for (int c = 0; c < 3; ++c)
                            acc[xx] = dot2(rr[xx + 2 - c], wp[a * 3 + c], acc[xx]);
                }
            }
        }
        float* op = out + (size_t)b * 784 + y * 28 + xb;
        #pragma unroll
        for (int xx = 0; xx < 4; ++xx) op[xx] = fast_tanh(acc[xx]);
    }
}

extern "C" void kernel_launch(void* const* d_in, const int* in_sizes, int n_in,
                              void* d_out, int out_size, void* d_ws, size_t ws_size,
                              hipStream_t stream) {
    const float* z   = (const float*)d_in[0];
    const int*   gi  = (const int*)d_in[1];
    const float* W1  = (const float*)d_in[2];
    const float* b1  = (const float*)d_in[3];
    const float* W2  = (const float*)d_in[4];
    const float* b2  = (const float*)d_in[5];
    const float* cw1 = (const float*)d_in[6];
    const float* cb1 = (const float*)d_in[7];
    const float* cw2 = (const float*)d_in[8];
    const float* cb2 = (const float*)d_in[9];
    const float* cw3 = (const float*)d_in[10];
    const float* cb3 = (const float*)d_in[11];
    int*      wsi = (int*)d_ws;
    u16*      h1f = (u16*)((char*)d_ws + WS_H1_OFF);
    u16*      h2g = (u16*)((char*)d_ws + WS_H2_OFF);
    _Float16* w2t = (_Float16*)((char*)d_ws + WS_W2T_OFF);
    u16*      apk1 = (u16*)((char*)d_ws + WS_WPK1_OFF);
    u16*      apk2 = (u16*)((char*)d_ws + WS_APK2_OFF);
    u32*      wpk3 = (u32*)((char*)d_ws + WS_WPK3_OFF);

    prep_kernel<<<NB_PREP + NGEN + 1, 256, 0, stream>>>(z, gi, W1, b1, W2, wsi,
                                                        h1f, w2t, cw1, cw2, cw3,
                                                        apk1, apk2, wpk3);
    fc2_kernel<<<MAXG * NCT, 256, 0, stream>>>(gi, w2t, b2, wsi, h1f, h2g);
    conv_kernel<<<MAXG * GRPS, 256, 0, stream>>>(gi, wsi, apk1, cb1, apk2, cb2,
                                                 wpk3, cb3, h2g, (float*)d_out);
}